// Round 9
// baseline (4394.103 us; speedup 1.0000x reference)
//
#include <hip/hip_runtime.h>
#include <hip/hip_bf16.h>

#define NP 131072
#define D 128
#define KC 2048
#define ITERS 5

#define TAU 0.03f      // bf16x3 top-2 gap below which we recheck in f64

typedef short bf16x8 __attribute__((ext_vector_type(8)));
typedef float f32x4 __attribute__((ext_vector_type(4)));

__device__ inline unsigned short f2bf(float x) {
    __hip_bfloat16 b = __float2bfloat16(x);
    return *reinterpret_cast<unsigned short*>(&b);
}
__device__ inline float bf2f(unsigned short u) {
    union { unsigned int i; float f; } c; c.i = ((unsigned int)u) << 16; return c.f;
}

// ---------------------------------------------------------------------------
// init: C64 / CT64 / packed bf16 split (Ch,Cl) from init centroids
// ---------------------------------------------------------------------------
__global__ void init_kernel(const float* __restrict__ initC,
                            double* __restrict__ C64, double* __restrict__ CT64,
                            unsigned short* __restrict__ Ch,
                            unsigned short* __restrict__ Cl) {
    int t = blockIdx.x * 256 + threadIdx.x;       // 262144
    float v = initC[t];
    C64[t] = (double)v;
    CT64[(size_t)(t & 127) * KC + (t >> 7)] = (double)v;
    unsigned short h = f2bf(v);
    Ch[t] = h;
    Cl[t] = f2bf(v - bf2f(h));
}

// wave-per-row point norms (f64 accumulate), stored f32 for the fast path
__global__ void xnorm_kernel(const float* __restrict__ A, float* __restrict__ n32) {
    int r = blockIdx.x * 4 + (threadIdx.x >> 6);
    int lane = threadIdx.x & 63;
    float2 v = *(const float2*)&A[(size_t)r * D + lane * 2];
    double s = (double)v.x * (double)v.x + (double)v.y * (double)v.y;
#pragma unroll
    for (int m = 1; m < 64; m <<= 1) s += __shfl_xor(s, m, 64);
    if (lane == 0) n32[r] = (float)s;
}

__global__ void cnorm_kernel(const double* __restrict__ C64,
                             double* __restrict__ n64, float* __restrict__ n32,
                             int* __restrict__ counter) {
    int r = blockIdx.x * 4 + (threadIdx.x >> 6);
    int lane = threadIdx.x & 63;
    double a = C64[(size_t)r * D + lane * 2];
    double b = C64[(size_t)r * D + lane * 2 + 1];
    double s = a * a + b * b;
#pragma unroll
    for (int m = 1; m < 64; m <<= 1) s += __shfl_xor(s, m, 64);
    if (lane == 0) { n64[r] = s; n32[r] = (float)s; }
    if (blockIdx.x == 0 && threadIdx.x == 0) *counter = 0;
}

// ---------------------------------------------------------------------------
// bf16x3 MFMA assign. Block = 128 points x 128 clusters/chunk, 4 waves.
// R9 restructure (R8: LDS-unit 5x oversubscribed vs MFMA, 2 barriers/ks):
//  - A-frags hoisted to 128 VGPRs once (invariant over ct) -> LDS reads halve
//  - A's 64KB LDS region reused as double-buffered B chunk (2 x 16KB):
//    stage B(t+1) global->reg early, ds_write after MFMA, ONE barrier/step.
// dot ~ xh*ch + xh*cl + xl*ch (3 MFMA). Cross-wave top-2 merge via LDS.
// ---------------------------------------------------------------------------
__global__ __launch_bounds__(256, 2)
void assign_kernel(const float* __restrict__ X,
                   const unsigned short* __restrict__ Ch,
                   const unsigned short* __restrict__ Cl,
                   const float* __restrict__ xnorm,
                   const float* __restrict__ cnorm,
                   int* __restrict__ labels,
                   int* __restrict__ list,
                   int* __restrict__ counter) {
    __shared__ __align__(16) char lds[65536];

    const int tid = threadIdx.x;
    const int lane = tid & 63;
    const int wid = tid >> 6;
    const int wrow = wid >> 1;          // 0..1
    const int wcol = wid & 1;           // 0..1
    const int t15 = lane & 15;
    const int q = lane >> 4;            // 0..3
    const int pbase = blockIdx.x * 128;

    // ---- stage A tile (128 rows x 128 k) into lds[0..64K), h/l, swizzled ----
#pragma unroll 4
    for (int i = 0; i < 16; i++) {
        int f = i * 256 + tid;          // float4-slot over 128 rows x 32 slots
        int row = f >> 5, c4 = f & 31;
        float4 v = *(const float4*)&X[(size_t)(pbase + row) * D + c4 * 4];
        unsigned short h0 = f2bf(v.x), h1 = f2bf(v.y), h2 = f2bf(v.z), h3 = f2bf(v.w);
        unsigned short l0 = f2bf(v.x - bf2f(h0)), l1 = f2bf(v.y - bf2f(h1));
        unsigned short l2 = f2bf(v.z - bf2f(h2)), l3 = f2bf(v.w - bf2f(h3));
        uint2 ph = { (unsigned)h0 | ((unsigned)h1 << 16), (unsigned)h2 | ((unsigned)h3 << 16) };
        uint2 pl = { (unsigned)l0 | ((unsigned)l1 << 16), (unsigned)l2 | ((unsigned)l3 << 16) };
        int ad = (row * 256 + c4 * 8) ^ ((row & 7) << 4);
        *(uint2*)(lds + ad) = ph;              // Ah region [0, 32K)
        *(uint2*)(lds + 32768 + ad) = pl;      // Al region [32K, 64K)
    }
    __syncthreads();

    // ---- hoist A-frags to registers (invariant across the whole ct loop) ----
    bf16x8 rah[4][4], ral[4][4];               // [rt][ks] : 128 VGPR
#pragma unroll
    for (int rt = 0; rt < 4; rt++) {
        int row = wrow * 64 + rt * 16 + t15;
        int sw = (row & 7) << 4;
#pragma unroll
        for (int ks = 0; ks < 4; ks++) {
            int ad = (row * 256 + ks * 64 + q * 16) ^ sw;
            rah[rt][ks] = *(const bf16x8*)(lds + ad);
            ral[rt][ks] = *(const bf16x8*)(lds + 32768 + ad);
        }
    }
    __syncthreads();   // all A reads done; region now reusable for B dbuf

    // B double buffers: buf c at lds + c*16K (Bh at +0, Bl at +8K)
    // staging slot mapping (per thread, 4 slots): f=i*256+tid, col=f>>3, c4=f&7
    int scol[4], sc4[4], sad[4];
#pragma unroll
    for (int i = 0; i < 4; i++) {
        int f = i * 256 + tid;
        scol[i] = f >> 3; sc4[i] = f & 7;
        sad[i] = (scol[i] * 64 + sc4[i] * 8) ^ ((scol[i] & 7) << 4);
    }

    // xnorm for my 16 row-slots
    float xnr[16];
#pragma unroll
    for (int rt = 0; rt < 4; rt++)
#pragma unroll
        for (int rg = 0; rg < 4; rg++)
            xnr[rt * 4 + rg] = xnorm[pbase + wrow * 64 + rt * 16 + q * 4 + rg];

    float b1[16], b2[16];
    int i1[16];
#pragma unroll
    for (int s = 0; s < 16; s++) { b1[s] = -INFINITY; b2[s] = -INFINITY; i1[s] = 0x7fffffff; }

    // prologue: stage B(ct=0, ks=0) into buf0
#pragma unroll
    for (int i = 0; i < 4; i++) {
        size_t go = (size_t)scol[i] * D + sc4[i] * 4;
        *(uint2*)(lds + sad[i]) = *(const uint2*)&Ch[go];
        *(uint2*)(lds + 8192 + sad[i]) = *(const uint2*)&Cl[go];
    }
    __syncthreads();

    for (int ct = 0; ct < KC / 128; ct++) {
        const int ctbase = ct * 128;
        f32x4 acc[4][4];
#pragma unroll
        for (int rt = 0; rt < 4; rt++)
#pragma unroll
            for (int cj = 0; cj < 4; cj++) acc[rt][cj] = (f32x4){0.f, 0.f, 0.f, 0.f};

#pragma unroll
        for (int ks = 0; ks < 4; ks++) {
            const int cur = ks & 1;                  // buf read this step
            // issue global loads for step t+1 (clamped at the very end)
            const int cn = (ks == 3) ? ((ct < 15) ? ct + 1 : 15) : ct;
            const int kn = (ks + 1) & 3;
            uint2 gh[4], gl[4];
#pragma unroll
            for (int i = 0; i < 4; i++) {
                size_t go = (size_t)(cn * 128 + scol[i]) * D + kn * 32 + sc4[i] * 4;
                gh[i] = *(const uint2*)&Ch[go];
                gl[i] = *(const uint2*)&Cl[go];
            }

            // MFMA on buf[cur]: b-frags streamed, a-frags from registers
            char* bhp = lds + cur * 16384;
            char* blp = lds + cur * 16384 + 8192;
#pragma unroll
            for (int cj = 0; cj < 4; cj++) {
                int col = wcol * 64 + cj * 16 + t15;
                int bd = (col * 64 + q * 16) ^ ((col & 7) << 4);
                bf16x8 bh = *(const bf16x8*)(bhp + bd);
                bf16x8 bl = *(const bf16x8*)(blp + bd);
#pragma unroll
                for (int rt = 0; rt < 4; rt++) {
                    acc[rt][cj] = __builtin_amdgcn_mfma_f32_16x16x32_bf16(rah[rt][ks], bh, acc[rt][cj], 0, 0, 0);
                    acc[rt][cj] = __builtin_amdgcn_mfma_f32_16x16x32_bf16(rah[rt][ks], bl, acc[rt][cj], 0, 0, 0);
                    acc[rt][cj] = __builtin_amdgcn_mfma_f32_16x16x32_bf16(ral[rt][ks], bh, acc[rt][cj], 0, 0, 0);
                }
            }

            // write staged regs into buf[cur^1] (read next step)
            char* nhp = lds + (cur ^ 1) * 16384;
#pragma unroll
            for (int i = 0; i < 4; i++) {
                *(uint2*)(nhp + sad[i]) = gh[i];
                *(uint2*)(nhp + 8192 + sad[i]) = gl[i];
            }
            __syncthreads();
        }

        // epilogue: s = 2*dot - xn - cn, running top-2
#pragma unroll
        for (int cj = 0; cj < 4; cj++) {
            int col = ctbase + wcol * 64 + cj * 16 + t15;
            float cnv = cnorm[col];
#pragma unroll
            for (int rt = 0; rt < 4; rt++)
#pragma unroll
                for (int rg = 0; rg < 4; rg++) {
                    int s = rt * 4 + rg;
                    float sv = 2.0f * acc[rt][cj][rg] - xnr[s] - cnv;
                    if (sv > b1[s]) { b2[s] = b1[s]; b1[s] = sv; i1[s] = col; }
                    else if (sv > b2[s]) b2[s] = sv;
                }
        }
    }

    // merge top-2 across the 16 t15 lanes of each q-group (within wave)
#pragma unroll
    for (int s = 0; s < 16; s++) {
#pragma unroll
        for (int m = 1; m < 16; m <<= 1) {
            float ob1 = __shfl_xor(b1[s], m, 64);
            int   oi  = __shfl_xor(i1[s], m, 64);
            float ob2 = __shfl_xor(b2[s], m, 64);
            if (ob1 > b1[s])      { b2[s] = fmaxf(b1[s], ob2); b1[s] = ob1; i1[s] = oi; }
            else if (ob1 < b1[s]) { b2[s] = fmaxf(b2[s], ob1); }
            else                  { b2[s] = b1[s]; i1[s] = (oi < i1[s]) ? oi : i1[s]; }
        }
    }

    // cross-wave merge (wcol 0 vs 1) via LDS region at +48K
    __syncthreads();
    float* mb1 = (float*)(lds + 49152);            // [2][128]
    float* mb2 = ((float*)(lds + 49152)) + 256;    // [2][128]
    int*   mi1 = (int*)(((float*)(lds + 49152)) + 512);  // [2][128]
    if (t15 == 0) {
#pragma unroll
        for (int rt = 0; rt < 4; rt++)
#pragma unroll
            for (int rg = 0; rg < 4; rg++) {
                int s = rt * 4 + rg;
                int row = wrow * 64 + rt * 16 + q * 4 + rg;
                mb1[wcol * 128 + row] = b1[s];
                mb2[wcol * 128 + row] = b2[s];
                mi1[wcol * 128 + row] = i1[s];
            }
    }
    __syncthreads();
    if (tid < 128) {
        float a1 = mb1[tid], a2 = mb2[tid];  int ai = mi1[tid];
        float c1 = mb1[128 + tid], c2 = mb2[128 + tid];  int ci = mi1[128 + tid];
        float best, second;  int bi;
        if (a1 > c1)      { best = a1; bi = ai; second = fmaxf(a2, c1); }
        else if (a1 < c1) { best = c1; bi = ci; second = fmaxf(c2, a1); }
        else              { best = a1; bi = (ai < ci) ? ai : ci; second = a1; }
        int p = pbase + tid;
        labels[p] = bi;
        if (best - second < TAU) {
            int idx = atomicAdd(counter, 1);
            list[idx] = p;
        }
    }
}

// ---------------------------------------------------------------------------
// f64 recheck of flagged points: exact argmax over all 2048 clusters.
// ---------------------------------------------------------------------------
__global__ void recheck_kernel(const float* __restrict__ X,
                               const double* __restrict__ CT64,
                               const double* __restrict__ cn64,
                               const int* __restrict__ list,
                               const int* __restrict__ counter,
                               int* __restrict__ labels) {
    __shared__ float xrow[D];
    __shared__ double rb[4];
    __shared__ int ri[4];
    int cnt = *counter;
    for (int ii = blockIdx.x; ii < cnt; ii += gridDim.x) {
        int p = list[ii];
        __syncthreads();
        if (threadIdx.x < D) xrow[threadIdx.x] = X[(size_t)p * D + threadIdx.x];
        __syncthreads();
        double xn = 0.0;
#pragma unroll 16
        for (int d = 0; d < D; d++) {
            double xv = (double)xrow[d];
            xn = fma(xv, xv, xn);
        }
        double best = -1.0e300;
        int bi = 0x7fffffff;
#pragma unroll
        for (int g = 0; g < 8; g++) {
            int c = threadIdx.x + 256 * g;
            double acc = 0.0;
#pragma unroll 16
            for (int d = 0; d < D; d++)
                acc = fma((double)xrow[d], CT64[(size_t)d * KC + c], acc);
            double s = 2.0 * acc - xn - cn64[c];
            if (s > best || (s == best && c < bi)) { best = s; bi = c; }
        }
#pragma unroll
        for (int m = 1; m < 64; m <<= 1) {
            double ob = __shfl_xor(best, m, 64);
            int oi = __shfl_xor(bi, m, 64);
            if (ob > best || (ob == best && oi < bi)) { best = ob; bi = oi; }
        }
        int w = threadIdx.x >> 6;
        if ((threadIdx.x & 63) == 0) { rb[w] = best; ri[w] = bi; }
        __syncthreads();
        if (threadIdx.x == 0) {
            double bb = rb[0]; int bbi = ri[0];
            for (int w2 = 1; w2 < 4; w2++)
                if (rb[w2] > bb || (rb[w2] == bb && ri[w2] < bbi)) { bb = rb[w2]; bbi = ri[w2]; }
            labels[p] = bbi;
        }
    }
}

// ---------------------------------------------------------------------------
// Deterministic f64 segment sums: block per cluster; 4 waves scan fixed
// quarter-ranges with int4 label loads; LDS combine in fixed wave order.
// ---------------------------------------------------------------------------
__global__ void accum_kernel(const float* __restrict__ X,
                             const int* __restrict__ labels,
                             double* __restrict__ sums,
                             int* __restrict__ counts) {
    __shared__ double sred[4][D];
    __shared__ int cred[4];
    const int k = blockIdx.x;
    const int lane = threadIdx.x & 63;
    const int w = threadIdx.x >> 6;
    const int base0 = w * (NP / 4);
    double s0 = 0.0, s1 = 0.0;
    int cnt = 0;
    for (int it = 0; it < (NP / 4) / 256; it++) {
        int4 lab = *(const int4*)&labels[base0 + it * 256 + lane * 4];
#pragma unroll
        for (int j = 0; j < 4; j++) {
            int lv = (j == 0) ? lab.x : (j == 1) ? lab.y : (j == 2) ? lab.z : lab.w;
            unsigned long long m = __ballot(lv == k);
            cnt += __popcll(m);
            while (m) {
                int b = __ffsll(m) - 1;
                m &= m - 1;
                int p = base0 + it * 256 + b * 4 + j;
                float2 v = *(const float2*)&X[(size_t)p * D + lane * 2];
                s0 += (double)v.x;
                s1 += (double)v.y;
            }
        }
    }
    sred[w][lane * 2] = s0;
    sred[w][lane * 2 + 1] = s1;
    if (lane == 0) cred[w] = cnt;
    __syncthreads();
    if (threadIdx.x < D) {
        int d = threadIdx.x;
        double s = ((sred[0][d] + sred[1][d]) + sred[2][d]) + sred[3][d];
        sums[(size_t)k * D + d] = s;
    }
    if (threadIdx.x == 0)
        counts[k] = ((cred[0] + cred[1]) + cred[2]) + cred[3];
}

// ---------------------------------------------------------------------------
// update: C = count>0 ? sum/count : 0 (f64); mirror to CT64 + bf16 h/l split
// ---------------------------------------------------------------------------
__global__ void update_kernel(const double* __restrict__ sums,
                              const int* __restrict__ counts,
                              double* __restrict__ C64, double* __restrict__ CT64,
                              unsigned short* __restrict__ Ch,
                              unsigned short* __restrict__ Cl,
                              float* __restrict__ outC) {
    int t = blockIdx.x * 256 + threadIdx.x;       // 262144
    int k = t >> 7;
    int n = counts[k];
    double v = (n > 0) ? sums[t] / (double)n : 0.0;
    C64[t] = v;
    CT64[(size_t)(t & 127) * KC + k] = v;
    float vf = (float)v;
    unsigned short h = f2bf(vf);
    Ch[t] = h;
    Cl[t] = f2bf(vf - bf2f(h));
    if (outC) outC[t] = vf;
}

__global__ void lab2f_kernel(const int* __restrict__ labels, float* __restrict__ out) {
    int t = blockIdx.x * 256 + threadIdx.x;
    out[t] = (float)labels[t];
}

extern "C" void kernel_launch(void* const* d_in, const int* in_sizes, int n_in,
                              void* d_out, int out_size, void* d_ws, size_t ws_size,
                              hipStream_t stream) {
    const float* X = (const float*)d_in[0];
    const float* initC = (const float*)d_in[1];
    float* out = (float*)d_out;

    char* w = (char*)d_ws;
    const size_t MB = 1u << 20;
    double* C64    = (double*)(w);                          // 2 MB
    double* S64    = (double*)(w + 2 * MB);                 // 2 MB
    double* CT64   = (double*)(w + 4 * MB);                 // 2 MB
    unsigned short* Ch = (unsigned short*)(w + 6 * MB);     // 512 KB
    unsigned short* Cl = (unsigned short*)(w + 6 * MB + 512 * 1024); // 512 KB
    float*  xn32   = (float*) (w + 7 * MB);                 // 512 KB
    int*    labels = (int*)   (w + 7 * MB + 512 * 1024);    // 512 KB
    int*    list   = (int*)   (w + 8 * MB);                 // 512 KB
    double* cn64   = (double*)(w + 8 * MB + 512 * 1024);    // 16 KB
    float*  cn32   = (float*) (w + 8 * MB + 528 * 1024);    // 8 KB
    int*    counts = (int*)   (w + 8 * MB + 536 * 1024);    // 8 KB
    int*    counter= (int*)   (w + 8 * MB + 544 * 1024);    // 4 B

    init_kernel<<<(KC * D) / 256, 256, 0, stream>>>(initC, C64, CT64, Ch, Cl);
    xnorm_kernel<<<NP / 4, 256, 0, stream>>>(X, xn32);

    for (int it = 0; it < ITERS; it++) {
        cnorm_kernel<<<KC / 4, 256, 0, stream>>>(C64, cn64, cn32, counter);
        assign_kernel<<<NP / 128, 256, 0, stream>>>(X, Ch, Cl, xn32, cn32, labels, list, counter);
        recheck_kernel<<<1024, 256, 0, stream>>>(X, CT64, cn64, list, counter, labels);
        accum_kernel<<<KC, 256, 0, stream>>>(X, labels, S64, counts);
        update_kernel<<<(KC * D) / 256, 256, 0, stream>>>(
            S64, counts, C64, CT64, Ch, Cl, (it == ITERS - 1) ? out : nullptr);
    }
    lab2f_kernel<<<NP / 256, 256, 0, stream>>>(labels, out + (size_t)KC * D);
}

// Round 10
// 4110.571 us; speedup vs baseline: 1.0690x; 1.0690x over previous
//
#include <hip/hip_runtime.h>
#include <hip/hip_bf16.h>

#define NP 131072
#define D 128
#define KC 2048
#define ITERS 5

#define TAU 0.03f      // bf16x3 top-2 gap below which we recheck in f64

typedef short bf16x8 __attribute__((ext_vector_type(8)));
typedef float f32x4 __attribute__((ext_vector_type(4)));

__device__ inline unsigned short f2bf(float x) {
    __hip_bfloat16 b = __float2bfloat16(x);
    return *reinterpret_cast<unsigned short*>(&b);
}
__device__ inline float bf2f(unsigned short u) {
    union { unsigned int i; float f; } c; c.i = ((unsigned int)u) << 16; return c.f;
}

// fragment-major slot for cluster k, dim d:
// g=k>>4, t15=k&15, ks=d>>5, q=(d>>3)&3, e=d&7
// slot = ((g*4+ks)*64 + q*16 + t15)*8 + e   (each b-frag = 64 lanes x 16B contiguous)
__device__ inline size_t bslot(int k, int d) {
    int g = k >> 4, t15 = k & 15, ks = d >> 5, q = (d >> 3) & 3, e = d & 7;
    return ((size_t)((g * 4 + ks) * 64 + q * 16 + t15)) * 8 + e;
}

// ---------------------------------------------------------------------------
// init: C64 / CT64 / fragment-major bf16 split (Bfh,Bfl)
// ---------------------------------------------------------------------------
__global__ void init_kernel(const float* __restrict__ initC,
                            double* __restrict__ C64, double* __restrict__ CT64,
                            unsigned short* __restrict__ Bfh,
                            unsigned short* __restrict__ Bfl) {
    int t = blockIdx.x * 256 + threadIdx.x;       // 262144
    float v = initC[t];
    C64[t] = (double)v;
    CT64[(size_t)(t & 127) * KC + (t >> 7)] = (double)v;
    unsigned short h = f2bf(v);
    size_t s = bslot(t >> 7, t & 127);
    Bfh[s] = h;
    Bfl[s] = f2bf(v - bf2f(h));
}

// wave-per-row point norms (f64 accumulate), stored f32 for the fast path
__global__ void xnorm_kernel(const float* __restrict__ A, float* __restrict__ n32) {
    int r = blockIdx.x * 4 + (threadIdx.x >> 6);
    int lane = threadIdx.x & 63;
    float2 v = *(const float2*)&A[(size_t)r * D + lane * 2];
    double s = (double)v.x * (double)v.x + (double)v.y * (double)v.y;
#pragma unroll
    for (int m = 1; m < 64; m <<= 1) s += __shfl_xor(s, m, 64);
    if (lane == 0) n32[r] = (float)s;
}

__global__ void cnorm_kernel(const double* __restrict__ C64,
                             double* __restrict__ n64, float* __restrict__ n32,
                             int* __restrict__ counter) {
    int r = blockIdx.x * 4 + (threadIdx.x >> 6);
    int lane = threadIdx.x & 63;
    double a = C64[(size_t)r * D + lane * 2];
    double b = C64[(size_t)r * D + lane * 2 + 1];
    double s = a * a + b * b;
#pragma unroll
    for (int m = 1; m < 64; m <<= 1) s += __shfl_xor(s, m, 64);
    if (lane == 0) { n64[r] = s; n32[r] = (float)s; }
    if (blockIdx.x == 0 && threadIdx.x == 0) *counter = 0;
}

// ---------------------------------------------------------------------------
// bf16x3 MFMA assign. Block = 128 points x 128 clusters/chunk, 4 waves.
// R10: B never touches LDS — b-frags loaded as coalesced dwordx4 from the
// fragment-major L2-resident Bfh/Bfl panel. ZERO barriers in the main loop
// (R8's lockstep 2-barrier/ks structure was the stall: MFMA floor 82us vs
// 385us measured). A-tile stays in LDS (64KB, h/l, XOR-swizzled).
// dot ~ xh*ch + xh*cl + xl*ch (3 MFMA). Cross-wave top-2 merge via LDS.
// ---------------------------------------------------------------------------
__global__ __launch_bounds__(256, 2)
void assign_kernel(const float* __restrict__ X,
                   const unsigned short* __restrict__ Bfh,
                   const unsigned short* __restrict__ Bfl,
                   const float* __restrict__ xnorm,
                   const float* __restrict__ cnorm,
                   int* __restrict__ labels,
                   int* __restrict__ list,
                   int* __restrict__ counter) {
    __shared__ __align__(16) char lds[65536];     // A tile: Ah [0,32K), Al [32K,64K)
    __shared__ float mb1[256], mb2[256];
    __shared__ int mi1[256];

    const int tid = threadIdx.x;
    const int lane = tid & 63;
    const int wid = tid >> 6;
    const int wrow = wid >> 1;          // 0..1
    const int wcol = wid & 1;           // 0..1
    const int t15 = lane & 15;
    const int q = lane >> 4;            // 0..3
    const int pbase = blockIdx.x * 128;

    // ---- stage A tile (128 rows x 128 k), split to bf16 h/l, swizzled ----
#pragma unroll 4
    for (int i = 0; i < 16; i++) {
        int f = i * 256 + tid;          // float4-slot over 128 rows x 32 slots
        int row = f >> 5, c4 = f & 31;
        float4 v = *(const float4*)&X[(size_t)(pbase + row) * D + c4 * 4];
        unsigned short h0 = f2bf(v.x), h1 = f2bf(v.y), h2 = f2bf(v.z), h3 = f2bf(v.w);
        unsigned short l0 = f2bf(v.x - bf2f(h0)), l1 = f2bf(v.y - bf2f(h1));
        unsigned short l2 = f2bf(v.z - bf2f(h2)), l3 = f2bf(v.w - bf2f(h3));
        uint2 ph = { (unsigned)h0 | ((unsigned)h1 << 16), (unsigned)h2 | ((unsigned)h3 << 16) };
        uint2 pl = { (unsigned)l0 | ((unsigned)l1 << 16), (unsigned)l2 | ((unsigned)l3 << 16) };
        int ad = (row * 256 + c4 * 8) ^ ((row & 7) << 4);
        *(uint2*)(lds + ad) = ph;
        *(uint2*)(lds + 32768 + ad) = pl;
    }
    __syncthreads();                    // A ready; no more barriers until merge

    // xnorm for my 16 row-slots
    float xnr[16];
#pragma unroll
    for (int rt = 0; rt < 4; rt++)
#pragma unroll
        for (int rg = 0; rg < 4; rg++)
            xnr[rt * 4 + rg] = xnorm[pbase + wrow * 64 + rt * 16 + q * 4 + rg];

    float b1[16], b2[16];
    int i1[16];
#pragma unroll
    for (int s = 0; s < 16; s++) { b1[s] = -INFINITY; b2[s] = -INFINITY; i1[s] = 0x7fffffff; }

    // per-thread a-frag LDS byte addresses (invariant)
    int aad[4][4];                       // [rt][ks]
#pragma unroll
    for (int rt = 0; rt < 4; rt++) {
        int row = wrow * 64 + rt * 16 + t15;
        int sw = (row & 7) << 4;
#pragma unroll
        for (int ks = 0; ks < 4; ks++)
            aad[rt][ks] = (row * 256 + ks * 64 + q * 16) ^ sw;
    }

    for (int ct = 0; ct < KC / 128; ct++) {
        const int ctbase = ct * 128;
        f32x4 acc[4][4];
#pragma unroll
        for (int rt = 0; rt < 4; rt++)
#pragma unroll
            for (int cj = 0; cj < 4; cj++) acc[rt][cj] = (f32x4){0.f, 0.f, 0.f, 0.f};

#pragma unroll
        for (int ks = 0; ks < 4; ks++) {
            // b-frags: coalesced 1KB loads from fragment-major panel (L2-hot)
            bf16x8 bh[4], bl[4];
#pragma unroll
            for (int cj = 0; cj < 4; cj++) {
                int g = ct * 8 + wcol * 4 + cj;
                size_t off = ((size_t)((g * 4 + ks) * 64 + lane)) * 8;
                bh[cj] = *(const bf16x8*)&Bfh[off];
                bl[cj] = *(const bf16x8*)&Bfl[off];
            }
            // a-frags from LDS
            bf16x8 ah[4], al[4];
#pragma unroll
            for (int rt = 0; rt < 4; rt++) {
                ah[rt] = *(const bf16x8*)(lds + aad[rt][ks]);
                al[rt] = *(const bf16x8*)(lds + 32768 + aad[rt][ks]);
            }
#pragma unroll
            for (int cj = 0; cj < 4; cj++)
#pragma unroll
                for (int rt = 0; rt < 4; rt++) {
                    acc[rt][cj] = __builtin_amdgcn_mfma_f32_16x16x32_bf16(ah[rt], bh[cj], acc[rt][cj], 0, 0, 0);
                    acc[rt][cj] = __builtin_amdgcn_mfma_f32_16x16x32_bf16(ah[rt], bl[cj], acc[rt][cj], 0, 0, 0);
                    acc[rt][cj] = __builtin_amdgcn_mfma_f32_16x16x32_bf16(al[rt], bh[cj], acc[rt][cj], 0, 0, 0);
                }
        }

        // epilogue: s = 2*dot - xn - cn, running top-2
#pragma unroll
        for (int cj = 0; cj < 4; cj++) {
            int col = ctbase + wcol * 64 + cj * 16 + t15;
            float cnv = cnorm[col];
#pragma unroll
            for (int rt = 0; rt < 4; rt++)
#pragma unroll
                for (int rg = 0; rg < 4; rg++) {
                    int s = rt * 4 + rg;
                    float sv = 2.0f * acc[rt][cj][rg] - xnr[s] - cnv;
                    if (sv > b1[s]) { b2[s] = b1[s]; b1[s] = sv; i1[s] = col; }
                    else if (sv > b2[s]) b2[s] = sv;
                }
        }
    }

    // merge top-2 across the 16 t15 lanes of each q-group (within wave)
#pragma unroll
    for (int s = 0; s < 16; s++) {
#pragma unroll
        for (int m = 1; m < 16; m <<= 1) {
            float ob1 = __shfl_xor(b1[s], m, 64);
            int   oi  = __shfl_xor(i1[s], m, 64);
            float ob2 = __shfl_xor(b2[s], m, 64);
            if (ob1 > b1[s])      { b2[s] = fmaxf(b1[s], ob2); b1[s] = ob1; i1[s] = oi; }
            else if (ob1 < b1[s]) { b2[s] = fmaxf(b2[s], ob1); }
            else                  { b2[s] = b1[s]; i1[s] = (oi < i1[s]) ? oi : i1[s]; }
        }
    }

    // cross-wave merge (wcol 0 vs 1)
    if (t15 == 0) {
#pragma unroll
        for (int rt = 0; rt < 4; rt++)
#pragma unroll
            for (int rg = 0; rg < 4; rg++) {
                int s = rt * 4 + rg;
                int row = wrow * 64 + rt * 16 + q * 4 + rg;
                mb1[wcol * 128 + row] = b1[s];
                mb2[wcol * 128 + row] = b2[s];
                mi1[wcol * 128 + row] = i1[s];
            }
    }
    __syncthreads();
    if (tid < 128) {
        float a1 = mb1[tid], a2 = mb2[tid];  int ai = mi1[tid];
        float c1 = mb1[128 + tid], c2 = mb2[128 + tid];  int ci = mi1[128 + tid];
        float best, second;  int bi;
        if (a1 > c1)      { best = a1; bi = ai; second = fmaxf(a2, c1); }
        else if (a1 < c1) { best = c1; bi = ci; second = fmaxf(c2, a1); }
        else              { best = a1; bi = (ai < ci) ? ai : ci; second = a1; }
        int p = pbase + tid;
        labels[p] = bi;
        if (best - second < TAU) {
            int idx = atomicAdd(counter, 1);
            list[idx] = p;
        }
    }
}

// ---------------------------------------------------------------------------
// f64 recheck of flagged points: exact argmax over all 2048 clusters.
// ---------------------------------------------------------------------------
__global__ void recheck_kernel(const float* __restrict__ X,
                               const double* __restrict__ CT64,
                               const double* __restrict__ cn64,
                               const int* __restrict__ list,
                               const int* __restrict__ counter,
                               int* __restrict__ labels) {
    __shared__ float xrow[D];
    __shared__ double rb[4];
    __shared__ int ri[4];
    int cnt = *counter;
    for (int ii = blockIdx.x; ii < cnt; ii += gridDim.x) {
        int p = list[ii];
        __syncthreads();
        if (threadIdx.x < D) xrow[threadIdx.x] = X[(size_t)p * D + threadIdx.x];
        __syncthreads();
        double xn = 0.0;
#pragma unroll 16
        for (int d = 0; d < D; d++) {
            double xv = (double)xrow[d];
            xn = fma(xv, xv, xn);
        }
        double best = -1.0e300;
        int bi = 0x7fffffff;
#pragma unroll
        for (int g = 0; g < 8; g++) {
            int c = threadIdx.x + 256 * g;
            double acc = 0.0;
#pragma unroll 16
            for (int d = 0; d < D; d++)
                acc = fma((double)xrow[d], CT64[(size_t)d * KC + c], acc);
            double s = 2.0 * acc - xn - cn64[c];
            if (s > best || (s == best && c < bi)) { best = s; bi = c; }
        }
#pragma unroll
        for (int m = 1; m < 64; m <<= 1) {
            double ob = __shfl_xor(best, m, 64);
            int oi = __shfl_xor(bi, m, 64);
            if (ob > best || (ob == best && oi < bi)) { best = ob; bi = oi; }
        }
        int w = threadIdx.x >> 6;
        if ((threadIdx.x & 63) == 0) { rb[w] = best; ri[w] = bi; }
        __syncthreads();
        if (threadIdx.x == 0) {
            double bb = rb[0]; int bbi = ri[0];
            for (int w2 = 1; w2 < 4; w2++)
                if (rb[w2] > bb || (rb[w2] == bb && ri[w2] < bbi)) { bb = rb[w2]; bbi = ri[w2]; }
            labels[p] = bbi;
        }
    }
}

// ---------------------------------------------------------------------------
// Deterministic f64 segment sums: block per cluster; 4 waves scan fixed
// quarter-ranges with int4 label loads; LDS combine in fixed wave order.
// ---------------------------------------------------------------------------
__global__ void accum_kernel(const float* __restrict__ X,
                             const int* __restrict__ labels,
                             double* __restrict__ sums,
                             int* __restrict__ counts) {
    __shared__ double sred[4][D];
    __shared__ int cred[4];
    const int k = blockIdx.x;
    const int lane = threadIdx.x & 63;
    const int w = threadIdx.x >> 6;
    const int base0 = w * (NP / 4);
    double s0 = 0.0, s1 = 0.0;
    int cnt = 0;
    for (int it = 0; it < (NP / 4) / 256; it++) {
        int4 lab = *(const int4*)&labels[base0 + it * 256 + lane * 4];
#pragma unroll
        for (int j = 0; j < 4; j++) {
            int lv = (j == 0) ? lab.x : (j == 1) ? lab.y : (j == 2) ? lab.z : lab.w;
            unsigned long long m = __ballot(lv == k);
            cnt += __popcll(m);
            while (m) {
                int b = __ffsll(m) - 1;
                m &= m - 1;
                int p = base0 + it * 256 + b * 4 + j;
                float2 v = *(const float2*)&X[(size_t)p * D + lane * 2];
                s0 += (double)v.x;
                s1 += (double)v.y;
            }
        }
    }
    sred[w][lane * 2] = s0;
    sred[w][lane * 2 + 1] = s1;
    if (lane == 0) cred[w] = cnt;
    __syncthreads();
    if (threadIdx.x < D) {
        int d = threadIdx.x;
        double s = ((sred[0][d] + sred[1][d]) + sred[2][d]) + sred[3][d];
        sums[(size_t)k * D + d] = s;
    }
    if (threadIdx.x == 0)
        counts[k] = ((cred[0] + cred[1]) + cred[2]) + cred[3];
}

// ---------------------------------------------------------------------------
// update: C = count>0 ? sum/count : 0 (f64); mirror to CT64 + fragment panel
// ---------------------------------------------------------------------------
__global__ void update_kernel(const double* __restrict__ sums,
                              const int* __restrict__ counts,
                              double* __restrict__ C64, double* __restrict__ CT64,
                              unsigned short* __restrict__ Bfh,
                              unsigned short* __restrict__ Bfl,
                              float* __restrict__ outC) {
    int t = blockIdx.x * 256 + threadIdx.x;       // 262144
    int k = t >> 7;
    int n = counts[k];
    double v = (n > 0) ? sums[t] / (double)n : 0.0;
    C64[t] = v;
    CT64[(size_t)(t & 127) * KC + k] = v;
    float vf = (float)v;
    unsigned short h = f2bf(vf);
    size_t s = bslot(k, t & 127);
    Bfh[s] = h;
    Bfl[s] = f2bf(vf - bf2f(h));
    if (outC) outC[t] = vf;
}

__global__ void lab2f_kernel(const int* __restrict__ labels, float* __restrict__ out) {
    int t = blockIdx.x * 256 + threadIdx.x;
    out[t] = (float)labels[t];
}

extern "C" void kernel_launch(void* const* d_in, const int* in_sizes, int n_in,
                              void* d_out, int out_size, void* d_ws, size_t ws_size,
                              hipStream_t stream) {
    const float* X = (const float*)d_in[0];
    const float* initC = (const float*)d_in[1];
    float* out = (float*)d_out;

    char* w = (char*)d_ws;
    const size_t MB = 1u << 20;
    double* C64    = (double*)(w);                          // 2 MB
    double* S64    = (double*)(w + 2 * MB);                 // 2 MB
    double* CT64   = (double*)(w + 4 * MB);                 // 2 MB
    unsigned short* Bfh = (unsigned short*)(w + 6 * MB);    // 512 KB
    unsigned short* Bfl = (unsigned short*)(w + 6 * MB + 512 * 1024); // 512 KB
    float*  xn32   = (float*) (w + 7 * MB);                 // 512 KB
    int*    labels = (int*)   (w + 7 * MB + 512 * 1024);    // 512 KB
    int*    list   = (int*)   (w + 8 * MB);                 // 512 KB
    double* cn64   = (double*)(w + 8 * MB + 512 * 1024);    // 16 KB
    float*  cn32   = (float*) (w + 8 * MB + 528 * 1024);    // 8 KB
    int*    counts = (int*)   (w + 8 * MB + 536 * 1024);    // 8 KB
    int*    counter= (int*)   (w + 8 * MB + 544 * 1024);    // 4 B

    init_kernel<<<(KC * D) / 256, 256, 0, stream>>>(initC, C64, CT64, Bfh, Bfl);
    xnorm_kernel<<<NP / 4, 256, 0, stream>>>(X, xn32);

    for (int it = 0; it < ITERS; it++) {
        cnorm_kernel<<<KC / 4, 256, 0, stream>>>(C64, cn64, cn32, counter);
        assign_kernel<<<NP / 128, 256, 0, stream>>>(X, Bfh, Bfl, xn32, cn32, labels, list, counter);
        recheck_kernel<<<1024, 256, 0, stream>>>(X, CT64, cn64, list, counter, labels);
        accum_kernel<<<KC, 256, 0, stream>>>(X, labels, S64, counts);
        update_kernel<<<(KC * D) / 256, 256, 0, stream>>>(
            S64, counts, C64, CT64, Bfh, Bfl, (it == ITERS - 1) ? out : nullptr);
    }
    lab2f_kernel<<<NP / 256, 256, 0, stream>>>(labels, out + (size_t)KC * D);
}

// Round 11
// 3356.812 us; speedup vs baseline: 1.3090x; 1.2245x over previous
//
#include <hip/hip_runtime.h>
#include <hip/hip_bf16.h>

#define NP 131072
#define D 128
#define KC 2048
#define ITERS 5

#define TAU 0.03f      // bf16x3 top-2 gap below which we recheck in f64

typedef short bf16x8 __attribute__((ext_vector_type(8)));
typedef float f32x4 __attribute__((ext_vector_type(4)));

__device__ inline unsigned short f2bf(float x) {
    __hip_bfloat16 b = __float2bfloat16(x);
    return *reinterpret_cast<unsigned short*>(&b);
}
__device__ inline float bf2f(unsigned short u) {
    union { unsigned int i; float f; } c; c.i = ((unsigned int)u) << 16; return c.f;
}

// ks-major fragment panel: for cluster k, dim d:
//   g=k>>4, t15=k&15, ks=d>>5, q=(d>>3)&3, e=d&7, lane=q*16+t15
//   ushort idx = ((ks*128+g)*2 + hl)*512 + lane*8 + e
// => for a (ct,ks) pair the 8 groups (h,l interleaved per group) are a
//    contiguous 16KB block: perfect for linear double-buffer staging.
__device__ inline size_t pslot(int k, int d, int hl) {
    int g = k >> 4, t15 = k & 15, ks = d >> 5, q = (d >> 3) & 3, e = d & 7;
    return ((size_t)((ks * 128 + g) * 2 + hl)) * 512 + (q * 16 + t15) * 8 + e;
}

// ---------------------------------------------------------------------------
// init: C64 / CT64 / ks-major bf16 split panel
// ---------------------------------------------------------------------------
__global__ void init_kernel(const float* __restrict__ initC,
                            double* __restrict__ C64, double* __restrict__ CT64,
                            unsigned short* __restrict__ Pn) {
    int t = blockIdx.x * 256 + threadIdx.x;       // 262144
    float v = initC[t];
    C64[t] = (double)v;
    CT64[(size_t)(t & 127) * KC + (t >> 7)] = (double)v;
    unsigned short h = f2bf(v);
    int k = t >> 7, d = t & 127;
    Pn[pslot(k, d, 0)] = h;
    Pn[pslot(k, d, 1)] = f2bf(v - bf2f(h));
}

__global__ void cnorm_kernel(const double* __restrict__ C64,
                             double* __restrict__ n64, float* __restrict__ n32,
                             int* __restrict__ counter) {
    int r = blockIdx.x * 4 + (threadIdx.x >> 6);
    int lane = threadIdx.x & 63;
    double a = C64[(size_t)r * D + lane * 2];
    double b = C64[(size_t)r * D + lane * 2 + 1];
    double s = a * a + b * b;
#pragma unroll
    for (int m = 1; m < 64; m <<= 1) s += __shfl_xor(s, m, 64);
    if (lane == 0) { n64[r] = s; n32[r] = (float)s; }
    if (blockIdx.x == 0 && threadIdx.x == 0) *counter = 0;
}

// ---------------------------------------------------------------------------
// bf16x3 MFMA assign. 512 threads = 8 waves (4 row-quarters x 2 col-halves),
// block = 128 points x all 2048 clusters.
// A-tile (h+l, K=128, 64KB LDS, XOR-swizzled) staged once.
// B: ks-major panel -> 2x16KB LDS double buffer, T14 reg-staging
// (global->reg at step top, ds_write after MFMA), ONE barrier per ks-step.
// xnorm dropped: argmax/gap invariant to the per-row -|x|^2 shift; any
// rounding-edge case falls under TAU and is f64-rechecked -> labels exact.
// ---------------------------------------------------------------------------
__global__ __launch_bounds__(512, 2)
void assign_kernel(const float* __restrict__ X,
                   const unsigned short* __restrict__ Pn,
                   const float* __restrict__ cnorm,
                   int* __restrict__ labels,
                   int* __restrict__ list,
                   int* __restrict__ counter) {
    __shared__ __align__(16) char ldsA[65536];    // Ah [0,32K), Al [32K,64K)
    __shared__ __align__(16) char ldsB[32768];    // B dbuf 2 x 16KB
    __shared__ float mb1[256], mb2[256];
    __shared__ int mi1[256];

    const int tid = threadIdx.x;        // 0..511
    const int lane = tid & 63;
    const int wid = tid >> 6;           // 0..7
    const int wrow = wid >> 1;          // 0..3 (32-row quarter)
    const int wcol = wid & 1;           // 0..1 (64-col half per chunk)
    const int t15 = lane & 15;
    const int q = lane >> 4;            // 0..3
    const int pbase = blockIdx.x * 128;

    // ---- stage A tile (128 rows x 128 k), split to bf16 h/l, swizzled ----
#pragma unroll 2
    for (int i = 0; i < 8; i++) {
        int f = i * 512 + tid;          // float4-slot over 128 rows x 32 slots
        int row = f >> 5, c4 = f & 31;
        float4 v = *(const float4*)&X[(size_t)(pbase + row) * D + c4 * 4];
        unsigned short h0 = f2bf(v.x), h1 = f2bf(v.y), h2 = f2bf(v.z), h3 = f2bf(v.w);
        unsigned short l0 = f2bf(v.x - bf2f(h0)), l1 = f2bf(v.y - bf2f(h1));
        unsigned short l2 = f2bf(v.z - bf2f(h2)), l3 = f2bf(v.w - bf2f(h3));
        uint2 ph = { (unsigned)h0 | ((unsigned)h1 << 16), (unsigned)h2 | ((unsigned)h3 << 16) };
        uint2 pl = { (unsigned)l0 | ((unsigned)l1 << 16), (unsigned)l2 | ((unsigned)l3 << 16) };
        int ad = (row * 256 + c4 * 8) ^ ((row & 7) << 4);
        *(uint2*)(ldsA + ad) = ph;
        *(uint2*)(ldsA + 32768 + ad) = pl;
    }

    // prologue: stage B step0 (ct=0, ks=0) into buf0
    {
        uint4 g0 = *(const uint4*)(Pn + (size_t)(0 * 512 + tid) * 8);
        uint4 g1 = *(const uint4*)(Pn + (size_t)(1 * 512 + tid) * 8);
        *(uint4*)(ldsB + (0 * 512 + tid) * 16) = g0;
        *(uint4*)(ldsB + (1 * 512 + tid) * 16) = g1;
    }
    __syncthreads();

    // invariant a-frag LDS byte addresses
    int aad[2][4];                       // [rt][ks]
#pragma unroll
    for (int rt = 0; rt < 2; rt++) {
        int row = wrow * 32 + rt * 16 + t15;
        int sw = (row & 7) << 4;
#pragma unroll
        for (int ks = 0; ks < 4; ks++)
            aad[rt][ks] = (row * 256 + ks * 64 + q * 16) ^ sw;
    }

    float b1[8], b2[8];
    int i1[8];
#pragma unroll
    for (int s = 0; s < 8; s++) { b1[s] = -INFINITY; b2[s] = -INFINITY; i1[s] = 0x7fffffff; }

    for (int ct = 0; ct < KC / 128; ct++) {
        f32x4 acc[2][4];
#pragma unroll
        for (int rt = 0; rt < 2; rt++)
#pragma unroll
            for (int cj = 0; cj < 4; cj++) acc[rt][cj] = (f32x4){0.f, 0.f, 0.f, 0.f};

#pragma unroll
        for (int ks = 0; ks < 4; ks++) {
            const int cur = ks & 1;
            // T14: issue next step's global loads NOW (land under the MFMAs)
            const int ksn = (ks + 1) & 3;
            const int ctn = (ks == 3) ? ((ct < 15) ? ct + 1 : 15) : ct;
            const size_t sb = (size_t)((ksn * 128 + ctn * 8) * 2) * 512;
            uint4 g0 = *(const uint4*)(Pn + sb + (size_t)(0 * 512 + tid) * 8);
            uint4 g1 = *(const uint4*)(Pn + sb + (size_t)(1 * 512 + tid) * 8);

            // a-frags for this ks (2 rt), then stream b-frags per cj
            bf16x8 ah[2], al[2];
#pragma unroll
            for (int rt = 0; rt < 2; rt++) {
                ah[rt] = *(const bf16x8*)(ldsA + aad[rt][ks]);
                al[rt] = *(const bf16x8*)(ldsA + 32768 + aad[rt][ks]);
            }
            const char* bp = ldsB + cur * 16384;
#pragma unroll
            for (int cj = 0; cj < 4; cj++) {
                int gl = wcol * 4 + cj;
                bf16x8 bh = *(const bf16x8*)(bp + gl * 2048 + lane * 16);
                bf16x8 bl = *(const bf16x8*)(bp + gl * 2048 + 1024 + lane * 16);
#pragma unroll
                for (int rt = 0; rt < 2; rt++) {
                    acc[rt][cj] = __builtin_amdgcn_mfma_f32_16x16x32_bf16(ah[rt], bh, acc[rt][cj], 0, 0, 0);
                    acc[rt][cj] = __builtin_amdgcn_mfma_f32_16x16x32_bf16(ah[rt], bl, acc[rt][cj], 0, 0, 0);
                    acc[rt][cj] = __builtin_amdgcn_mfma_f32_16x16x32_bf16(al[rt], bh, acc[rt][cj], 0, 0, 0);
                }
            }

            // write staged regs into the other buffer, one barrier per step
            char* np = ldsB + (cur ^ 1) * 16384;
            *(uint4*)(np + (0 * 512 + tid) * 16) = g0;
            *(uint4*)(np + (1 * 512 + tid) * 16) = g1;
            __syncthreads();
        }

        // epilogue: s = 2*dot - cn (xn dropped), running top-2
#pragma unroll
        for (int cj = 0; cj < 4; cj++) {
            int col = ct * 128 + wcol * 64 + cj * 16 + t15;
            float cnv = cnorm[col];
#pragma unroll
            for (int rt = 0; rt < 2; rt++)
#pragma unroll
                for (int rg = 0; rg < 4; rg++) {
                    int s = rt * 4 + rg;
                    float sv = 2.0f * acc[rt][cj][rg] - cnv;
                    if (sv > b1[s]) { b2[s] = b1[s]; b1[s] = sv; i1[s] = col; }
                    else if (sv > b2[s]) b2[s] = sv;
                }
        }
    }

    // merge top-2 across the 16 t15 lanes of each q-group (within wave)
#pragma unroll
    for (int s = 0; s < 8; s++) {
#pragma unroll
        for (int m = 1; m < 16; m <<= 1) {
            float ob1 = __shfl_xor(b1[s], m, 64);
            int   oi  = __shfl_xor(i1[s], m, 64);
            float ob2 = __shfl_xor(b2[s], m, 64);
            if (ob1 > b1[s])      { b2[s] = fmaxf(b1[s], ob2); b1[s] = ob1; i1[s] = oi; }
            else if (ob1 < b1[s]) { b2[s] = fmaxf(b2[s], ob1); }
            else                  { b2[s] = b1[s]; i1[s] = (oi < i1[s]) ? oi : i1[s]; }
        }
    }

    // cross-wave merge (wcol 0 vs 1)
    if (t15 == 0) {
#pragma unroll
        for (int rt = 0; rt < 2; rt++)
#pragma unroll
            for (int rg = 0; rg < 4; rg++) {
                int s = rt * 4 + rg;
                int row = wrow * 32 + rt * 16 + q * 4 + rg;
                mb1[wcol * 128 + row] = b1[s];
                mb2[wcol * 128 + row] = b2[s];
                mi1[wcol * 128 + row] = i1[s];
            }
    }
    __syncthreads();
    if (tid < 128) {
        float a1 = mb1[tid], a2 = mb2[tid];  int ai = mi1[tid];
        float c1 = mb1[128 + tid], c2 = mb2[128 + tid];  int ci = mi1[128 + tid];
        float best, second;  int bi;
        if (a1 > c1)      { best = a1; bi = ai; second = fmaxf(a2, c1); }
        else if (a1 < c1) { best = c1; bi = ci; second = fmaxf(c2, a1); }
        else              { best = a1; bi = (ai < ci) ? ai : ci; second = a1; }
        int p = pbase + tid;
        labels[p] = bi;
        if (best - second < TAU) {
            int idx = atomicAdd(counter, 1);
            list[idx] = p;
        }
    }
}

// ---------------------------------------------------------------------------
// f64 recheck of flagged points: exact argmax over all 2048 clusters.
// ---------------------------------------------------------------------------
__global__ void recheck_kernel(const float* __restrict__ X,
                               const double* __restrict__ CT64,
                               const double* __restrict__ cn64,
                               const int* __restrict__ list,
                               const int* __restrict__ counter,
                               int* __restrict__ labels) {
    __shared__ float xrow[D];
    __shared__ double rb[4];
    __shared__ int ri[4];
    int cnt = *counter;
    for (int ii = blockIdx.x; ii < cnt; ii += gridDim.x) {
        int p = list[ii];
        __syncthreads();
        if (threadIdx.x < D) xrow[threadIdx.x] = X[(size_t)p * D + threadIdx.x];
        __syncthreads();
        double xn = 0.0;
#pragma unroll 16
        for (int d = 0; d < D; d++) {
            double xv = (double)xrow[d];
            xn = fma(xv, xv, xn);
        }
        double best = -1.0e300;
        int bi = 0x7fffffff;
#pragma unroll
        for (int g = 0; g < 8; g++) {
            int c = threadIdx.x + 256 * g;
            double acc = 0.0;
#pragma unroll 16
            for (int d = 0; d < D; d++)
                acc = fma((double)xrow[d], CT64[(size_t)d * KC + c], acc);
            double s = 2.0 * acc - xn - cn64[c];
            if (s > best || (s == best && c < bi)) { best = s; bi = c; }
        }
#pragma unroll
        for (int m = 1; m < 64; m <<= 1) {
            double ob = __shfl_xor(best, m, 64);
            int oi = __shfl_xor(bi, m, 64);
            if (ob > best || (ob == best && oi < bi)) { best = ob; bi = oi; }
        }
        int w = threadIdx.x >> 6;
        if ((threadIdx.x & 63) == 0) { rb[w] = best; ri[w] = bi; }
        __syncthreads();
        if (threadIdx.x == 0) {
            double bb = rb[0]; int bbi = ri[0];
            for (int w2 = 1; w2 < 4; w2++)
                if (rb[w2] > bb || (rb[w2] == bb && ri[w2] < bbi)) { bb = rb[w2]; bbi = ri[w2]; }
            labels[p] = bbi;
        }
    }
}

// ---------------------------------------------------------------------------
// Deterministic f64 segment sums: block per cluster; 4 waves scan fixed
// quarter-ranges with int4 label loads; LDS combine in fixed wave order.
// ---------------------------------------------------------------------------
__global__ void accum_kernel(const float* __restrict__ X,
                             const int* __restrict__ labels,
                             double* __restrict__ sums,
                             int* __restrict__ counts) {
    __shared__ double sred[4][D];
    __shared__ int cred[4];
    const int k = blockIdx.x;
    const int lane = threadIdx.x & 63;
    const int w = threadIdx.x >> 6;
    const int base0 = w * (NP / 4);
    double s0 = 0.0, s1 = 0.0;
    int cnt = 0;
    for (int it = 0; it < (NP / 4) / 256; it++) {
        int4 lab = *(const int4*)&labels[base0 + it * 256 + lane * 4];
#pragma unroll
        for (int j = 0; j < 4; j++) {
            int lv = (j == 0) ? lab.x : (j == 1) ? lab.y : (j == 2) ? lab.z : lab.w;
            unsigned long long m = __ballot(lv == k);
            cnt += __popcll(m);
            while (m) {
                int b = __ffsll(m) - 1;
                m &= m - 1;
                int p = base0 + it * 256 + b * 4 + j;
                float2 v = *(const float2*)&X[(size_t)p * D + lane * 2];
                s0 += (double)v.x;
                s1 += (double)v.y;
            }
        }
    }
    sred[w][lane * 2] = s0;
    sred[w][lane * 2 + 1] = s1;
    if (lane == 0) cred[w] = cnt;
    __syncthreads();
    if (threadIdx.x < D) {
        int d = threadIdx.x;
        double s = ((sred[0][d] + sred[1][d]) + sred[2][d]) + sred[3][d];
        sums[(size_t)k * D + d] = s;
    }
    if (threadIdx.x == 0)
        counts[k] = ((cred[0] + cred[1]) + cred[2]) + cred[3];
}

// ---------------------------------------------------------------------------
// update: C = count>0 ? sum/count : 0 (f64); mirror to CT64 + ks-major panel
// ---------------------------------------------------------------------------
__global__ void update_kernel(const double* __restrict__ sums,
                              const int* __restrict__ counts,
                              double* __restrict__ C64, double* __restrict__ CT64,
                              unsigned short* __restrict__ Pn,
                              float* __restrict__ outC) {
    int t = blockIdx.x * 256 + threadIdx.x;       // 262144
    int k = t >> 7;
    int n = counts[k];
    double v = (n > 0) ? sums[t] / (double)n : 0.0;
    C64[t] = v;
    CT64[(size_t)(t & 127) * KC + k] = v;
    float vf = (float)v;
    unsigned short h = f2bf(vf);
    int d = t & 127;
    Pn[pslot(k, d, 0)] = h;
    Pn[pslot(k, d, 1)] = f2bf(vf - bf2f(h));
    if (outC) outC[t] = vf;
}

__global__ void lab2f_kernel(const int* __restrict__ labels, float* __restrict__ out) {
    int t = blockIdx.x * 256 + threadIdx.x;
    out[t] = (float)labels[t];
}

extern "C" void kernel_launch(void* const* d_in, const int* in_sizes, int n_in,
                              void* d_out, int out_size, void* d_ws, size_t ws_size,
                              hipStream_t stream) {
    const float* X = (const float*)d_in[0];
    const float* initC = (const float*)d_in[1];
    float* out = (float*)d_out;

    char* w = (char*)d_ws;
    const size_t MB = 1u << 20;
    double* C64    = (double*)(w);                          // 2 MB
    double* S64    = (double*)(w + 2 * MB);                 // 2 MB
    double* CT64   = (double*)(w + 4 * MB);                 // 2 MB
    unsigned short* Pn = (unsigned short*)(w + 6 * MB);     // 1 MB (ks-major panel)
    int*    labels = (int*)   (w + 7 * MB);                 // 512 KB
    int*    list   = (int*)   (w + 7 * MB + 512 * 1024);    // 512 KB
    double* cn64   = (double*)(w + 8 * MB);                 // 16 KB
    float*  cn32   = (float*) (w + 8 * MB + 16 * 1024);     // 8 KB
    int*    counts = (int*)   (w + 8 * MB + 24 * 1024);     // 8 KB
    int*    counter= (int*)   (w + 8 * MB + 32 * 1024);     // 4 B

    init_kernel<<<(KC * D) / 256, 256, 0, stream>>>(initC, C64, CT64, Pn);

    for (int it = 0; it < ITERS; it++) {
        cnorm_kernel<<<KC / 4, 256, 0, stream>>>(C64, cn64, cn32, counter);
        assign_kernel<<<NP / 128, 512, 0, stream>>>(X, Pn, cn32, labels, list, counter);
        recheck_kernel<<<1024, 256, 0, stream>>>(X, CT64, cn64, list, counter, labels);
        accum_kernel<<<KC, 256, 0, stream>>>(X, labels, S64, counts);
        update_kernel<<<(KC * D) / 256, 256, 0, stream>>>(
            S64, counts, C64, CT64, Pn, (it == ITERS - 1) ? out : nullptr);
    }
    lab2f_kernel<<<NP / 256, 256, 0, stream>>>(labels, out + (size_t)KC * D);
}

// Round 12
// 3227.769 us; speedup vs baseline: 1.3613x; 1.0400x over previous
//
#include <hip/hip_runtime.h>
#include <hip/hip_bf16.h>

#define NP 131072
#define D 128
#define KC 2048
#define ITERS 5

#define TAU 0.03f      // bf16x3 top-2 gap below which we recheck in f64

typedef short bf16x8 __attribute__((ext_vector_type(8)));
typedef float f32x4 __attribute__((ext_vector_type(4)));

__device__ inline unsigned short f2bf(float x) {
    __hip_bfloat16 b = __float2bfloat16(x);
    return *reinterpret_cast<unsigned short*>(&b);
}
__device__ inline float bf2f(unsigned short u) {
    union { unsigned int i; float f; } c; c.i = ((unsigned int)u) << 16; return c.f;
}

// ks-major fragment panel: for cluster k, dim d:
//   g=k>>4, t15=k&15, ks=d>>5, q=(d>>3)&3, e=d&7, lane=q*16+t15
//   ushort idx = ((ks*128+g)*2 + hl)*512 + lane*8 + e
__device__ inline size_t pslot(int k, int d, int hl) {
    int g = k >> 4, t15 = k & 15, ks = d >> 5, q = (d >> 3) & 3, e = d & 7;
    return ((size_t)((ks * 128 + g) * 2 + hl)) * 512 + (q * 16 + t15) * 8 + e;
}

// ---------------------------------------------------------------------------
// init: C64 / CT64 / ks-major bf16 split panel
// ---------------------------------------------------------------------------
__global__ void init_kernel(const float* __restrict__ initC,
                            double* __restrict__ C64, double* __restrict__ CT64,
                            unsigned short* __restrict__ Pn) {
    int t = blockIdx.x * 256 + threadIdx.x;       // 262144
    float v = initC[t];
    C64[t] = (double)v;
    CT64[(size_t)(t & 127) * KC + (t >> 7)] = (double)v;
    unsigned short h = f2bf(v);
    int k = t >> 7, d = t & 127;
    Pn[pslot(k, d, 0)] = h;
    Pn[pslot(k, d, 1)] = f2bf(v - bf2f(h));
}

__global__ void cnorm_kernel(const double* __restrict__ C64,
                             double* __restrict__ n64, float* __restrict__ n32,
                             int* __restrict__ counter) {
    int r = blockIdx.x * 4 + (threadIdx.x >> 6);
    int lane = threadIdx.x & 63;
    double a = C64[(size_t)r * D + lane * 2];
    double b = C64[(size_t)r * D + lane * 2 + 1];
    double s = a * a + b * b;
#pragma unroll
    for (int m = 1; m < 64; m <<= 1) s += __shfl_xor(s, m, 64);
    if (lane == 0) { n64[r] = s; n32[r] = (float)s; }
    if (blockIdx.x == 0 && threadIdx.x == 0) *counter = 0;
}

// ---------------------------------------------------------------------------
// bf16x3 MFMA assign. 512 threads = 8 waves (4 row-quarters x 2 col-halves),
// block = 128 points x all 2048 clusters.
// R12: ZERO barriers / ZERO LDS in the main loop.
//  - a-frags hoisted to 64 VGPRs (rt=2 -> fits; R9's spill was rt=4's 128)
//  - b-frags read DIRECTLY from the L2-resident ks-major panel (byte-identical
//    to R11's LDS-staged values -> labels unchanged); 4 same-wcol waves share
//    via L1; 24 MFMAs per ks hide the L2 latency.
// ---------------------------------------------------------------------------
__global__ __launch_bounds__(512, 2)
void assign_kernel(const float* __restrict__ X,
                   const unsigned short* __restrict__ Pn,
                   const float* __restrict__ cnorm,
                   int* __restrict__ labels,
                   int* __restrict__ list,
                   int* __restrict__ counter) {
    __shared__ __align__(16) char ldsA[65536];    // Ah [0,32K), Al [32K,64K)
    __shared__ float mb1[256], mb2[256];
    __shared__ int mi1[256];

    const int tid = threadIdx.x;        // 0..511
    const int lane = tid & 63;
    const int wid = tid >> 6;           // 0..7
    const int wrow = wid >> 1;          // 0..3 (32-row quarter)
    const int wcol = wid & 1;           // 0..1 (64-col half per chunk)
    const int t15 = lane & 15;
    const int q = lane >> 4;            // 0..3
    const int pbase = blockIdx.x * 128;

    // ---- stage A tile (128 rows x 128 k), split to bf16 h/l, swizzled ----
#pragma unroll 2
    for (int i = 0; i < 8; i++) {
        int f = i * 512 + tid;          // float4-slot over 128 rows x 32 slots
        int row = f >> 5, c4 = f & 31;
        float4 v = *(const float4*)&X[(size_t)(pbase + row) * D + c4 * 4];
        unsigned short h0 = f2bf(v.x), h1 = f2bf(v.y), h2 = f2bf(v.z), h3 = f2bf(v.w);
        unsigned short l0 = f2bf(v.x - bf2f(h0)), l1 = f2bf(v.y - bf2f(h1));
        unsigned short l2 = f2bf(v.z - bf2f(h2)), l3 = f2bf(v.w - bf2f(h3));
        uint2 ph = { (unsigned)h0 | ((unsigned)h1 << 16), (unsigned)h2 | ((unsigned)h3 << 16) };
        uint2 pl = { (unsigned)l0 | ((unsigned)l1 << 16), (unsigned)l2 | ((unsigned)l3 << 16) };
        int ad = (row * 256 + c4 * 8) ^ ((row & 7) << 4);
        *(uint2*)(ldsA + ad) = ph;
        *(uint2*)(ldsA + 32768 + ad) = pl;
    }
    __syncthreads();

    // ---- hoist a-frags: rt=2 x ks=4 x {h,l} = 16 bf16x8 = 64 VGPR ----
    bf16x8 rah[2][4], ral[2][4];
#pragma unroll
    for (int rt = 0; rt < 2; rt++) {
        int row = wrow * 32 + rt * 16 + t15;
        int sw = (row & 7) << 4;
#pragma unroll
        for (int ks = 0; ks < 4; ks++) {
            int ad = (row * 256 + ks * 64 + q * 16) ^ sw;
            rah[rt][ks] = *(const bf16x8*)(ldsA + ad);
            ral[rt][ks] = *(const bf16x8*)(ldsA + 32768 + ad);
        }
    }

    float b1[8], b2[8];
    int i1[8];
#pragma unroll
    for (int s = 0; s < 8; s++) { b1[s] = -INFINITY; b2[s] = -INFINITY; i1[s] = 0x7fffffff; }

    // base ushort offset for this thread's b-frag reads: lane*8 within group
    const unsigned short* Pb = Pn + lane * 8;

    for (int ct = 0; ct < KC / 128; ct++) {
        f32x4 acc[2][4];
#pragma unroll
        for (int rt = 0; rt < 2; rt++)
#pragma unroll
            for (int cj = 0; cj < 4; cj++) acc[rt][cj] = (f32x4){0.f, 0.f, 0.f, 0.f};

#pragma unroll
        for (int ks = 0; ks < 4; ks++) {
#pragma unroll
            for (int cj = 0; cj < 4; cj++) {
                int g = ks * 128 + ct * 8 + wcol * 4 + cj;
                const unsigned short* bp = Pb + (size_t)g * 1024;
                bf16x8 bh = *(const bf16x8*)(bp);
                bf16x8 bl = *(const bf16x8*)(bp + 512);
#pragma unroll
                for (int rt = 0; rt < 2; rt++) {
                    acc[rt][cj] = __builtin_amdgcn_mfma_f32_16x16x32_bf16(rah[rt][ks], bh, acc[rt][cj], 0, 0, 0);
                    acc[rt][cj] = __builtin_amdgcn_mfma_f32_16x16x32_bf16(rah[rt][ks], bl, acc[rt][cj], 0, 0, 0);
                    acc[rt][cj] = __builtin_amdgcn_mfma_f32_16x16x32_bf16(ral[rt][ks], bh, acc[rt][cj], 0, 0, 0);
                }
            }
        }

        // epilogue: s = 2*dot - cn (xn dropped: row-shift invariant), top-2
#pragma unroll
        for (int cj = 0; cj < 4; cj++) {
            int col = ct * 128 + wcol * 64 + cj * 16 + t15;
            float cnv = cnorm[col];
#pragma unroll
            for (int rt = 0; rt < 2; rt++)
#pragma unroll
                for (int rg = 0; rg < 4; rg++) {
                    int s = rt * 4 + rg;
                    float sv = 2.0f * acc[rt][cj][rg] - cnv;
                    if (sv > b1[s]) { b2[s] = b1[s]; b1[s] = sv; i1[s] = col; }
                    else if (sv > b2[s]) b2[s] = sv;
                }
        }
    }

    // merge top-2 across the 16 t15 lanes of each q-group (within wave)
#pragma unroll
    for (int s = 0; s < 8; s++) {
#pragma unroll
        for (int m = 1; m < 16; m <<= 1) {
            float ob1 = __shfl_xor(b1[s], m, 64);
            int   oi  = __shfl_xor(i1[s], m, 64);
            float ob2 = __shfl_xor(b2[s], m, 64);
            if (ob1 > b1[s])      { b2[s] = fmaxf(b1[s], ob2); b1[s] = ob1; i1[s] = oi; }
            else if (ob1 < b1[s]) { b2[s] = fmaxf(b2[s], ob1); }
            else                  { b2[s] = b1[s]; i1[s] = (oi < i1[s]) ? oi : i1[s]; }
        }
    }

    // cross-wave merge (wcol 0 vs 1)
    if (t15 == 0) {
#pragma unroll
        for (int rt = 0; rt < 2; rt++)
#pragma unroll
            for (int rg = 0; rg < 4; rg++) {
                int s = rt * 4 + rg;
                int row = wrow * 32 + rt * 16 + q * 4 + rg;
                mb1[wcol * 128 + row] = b1[s];
                mb2[wcol * 128 + row] = b2[s];
                mi1[wcol * 128 + row] = i1[s];
            }
    }
    __syncthreads();
    if (tid < 128) {
        float a1 = mb1[tid], a2 = mb2[tid];  int ai = mi1[tid];
        float c1 = mb1[128 + tid], c2 = mb2[128 + tid];  int ci = mi1[128 + tid];
        float best, second;  int bi;
        if (a1 > c1)      { best = a1; bi = ai; second = fmaxf(a2, c1); }
        else if (a1 < c1) { best = c1; bi = ci; second = fmaxf(c2, a1); }
        else              { best = a1; bi = (ai < ci) ? ai : ci; second = a1; }
        int p = pbase + tid;
        labels[p] = bi;
        if (best - second < TAU) {
            int idx = atomicAdd(counter, 1);
            list[idx] = p;
        }
    }
}

// ---------------------------------------------------------------------------
// f64 recheck of flagged points: exact argmax over all 2048 clusters.
// ---------------------------------------------------------------------------
__global__ void recheck_kernel(const float* __restrict__ X,
                               const double* __restrict__ CT64,
                               const double* __restrict__ cn64,
                               const int* __restrict__ list,
                               const int* __restrict__ counter,
                               int* __restrict__ labels) {
    __shared__ float xrow[D];
    __shared__ double rb[4];
    __shared__ int ri[4];
    int cnt = *counter;
    for (int ii = blockIdx.x; ii < cnt; ii += gridDim.x) {
        int p = list[ii];
        __syncthreads();
        if (threadIdx.x < D) xrow[threadIdx.x] = X[(size_t)p * D + threadIdx.x];
        __syncthreads();
        double xn = 0.0;
#pragma unroll 16
        for (int d = 0; d < D; d++) {
            double xv = (double)xrow[d];
            xn = fma(xv, xv, xn);
        }
        double best = -1.0e300;
        int bi = 0x7fffffff;
#pragma unroll
        for (int g = 0; g < 8; g++) {
            int c = threadIdx.x + 256 * g;
            double acc = 0.0;
#pragma unroll 16
            for (int d = 0; d < D; d++)
                acc = fma((double)xrow[d], CT64[(size_t)d * KC + c], acc);
            double s = 2.0 * acc - xn - cn64[c];
            if (s > best || (s == best && c < bi)) { best = s; bi = c; }
        }
#pragma unroll
        for (int m = 1; m < 64; m <<= 1) {
            double ob = __shfl_xor(best, m, 64);
            int oi = __shfl_xor(bi, m, 64);
            if (ob > best || (ob == best && oi < bi)) { best = ob; bi = oi; }
        }
        int w = threadIdx.x >> 6;
        if ((threadIdx.x & 63) == 0) { rb[w] = best; ri[w] = bi; }
        __syncthreads();
        if (threadIdx.x == 0) {
            double bb = rb[0]; int bbi = ri[0];
            for (int w2 = 1; w2 < 4; w2++)
                if (rb[w2] > bb || (rb[w2] == bb && ri[w2] < bbi)) { bb = rb[w2]; bbi = ri[w2]; }
            labels[p] = bbi;
        }
    }
}

// ---------------------------------------------------------------------------
// Deterministic f64 segment sums: block per cluster; 4 waves scan fixed
// quarter-ranges with int4 label loads; LDS combine in fixed wave order.
// ---------------------------------------------------------------------------
__global__ void accum_kernel(const float* __restrict__ X,
                             const int* __restrict__ labels,
                             double* __restrict__ sums,
                             int* __restrict__ counts) {
    __shared__ double sred[4][D];
    __shared__ int cred[4];
    const int k = blockIdx.x;
    const int lane = threadIdx.x & 63;
    const int w = threadIdx.x >> 6;
    const int base0 = w * (NP / 4);
    double s0 = 0.0, s1 = 0.0;
    int cnt = 0;
    for (int it = 0; it < (NP / 4) / 256; it++) {
        int4 lab = *(const int4*)&labels[base0 + it * 256 + lane * 4];
#pragma unroll
        for (int j = 0; j < 4; j++) {
            int lv = (j == 0) ? lab.x : (j == 1) ? lab.y : (j == 2) ? lab.z : lab.w;
            unsigned long long m = __ballot(lv == k);
            cnt += __popcll(m);
            while (m) {
                int b = __ffsll(m) - 1;
                m &= m - 1;
                int p = base0 + it * 256 + b * 4 + j;
                float2 v = *(const float2*)&X[(size_t)p * D + lane * 2];
                s0 += (double)v.x;
                s1 += (double)v.y;
            }
        }
    }
    sred[w][lane * 2] = s0;
    sred[w][lane * 2 + 1] = s1;
    if (lane == 0) cred[w] = cnt;
    __syncthreads();
    if (threadIdx.x < D) {
        int d = threadIdx.x;
        double s = ((sred[0][d] + sred[1][d]) + sred[2][d]) + sred[3][d];
        sums[(size_t)k * D + d] = s;
    }
    if (threadIdx.x == 0)
        counts[k] = ((cred[0] + cred[1]) + cred[2]) + cred[3];
}

// ---------------------------------------------------------------------------
// update: C = count>0 ? sum/count : 0 (f64); mirror to CT64 + ks-major panel
// ---------------------------------------------------------------------------
__global__ void update_kernel(const double* __restrict__ sums,
                              const int* __restrict__ counts,
                              double* __restrict__ C64, double* __restrict__ CT64,
                              unsigned short* __restrict__ Pn,
                              float* __restrict__ outC) {
    int t = blockIdx.x * 256 + threadIdx.x;       // 262144
    int k = t >> 7;
    int n = counts[k];
    double v = (n > 0) ? sums[t] / (double)n : 0.0;
    C64[t] = v;
    CT64[(size_t)(t & 127) * KC + k] = v;
    float vf = (float)v;
    unsigned short h = f2bf(vf);
    int d = t & 127;
    Pn[pslot(k, d, 0)] = h;
    Pn[pslot(k, d, 1)] = f2bf(vf - bf2f(h));
    if (outC) outC[t] = vf;
}

__global__ void lab2f_kernel(const int* __restrict__ labels, float* __restrict__ out) {
    int t = blockIdx.x * 256 + threadIdx.x;
    out[t] = (float)labels[t];
}

extern "C" void kernel_launch(void* const* d_in, const int* in_sizes, int n_in,
                              void* d_out, int out_size, void* d_ws, size_t ws_size,
                              hipStream_t stream) {
    const float* X = (const float*)d_in[0];
    const float* initC = (const float*)d_in[1];
    float* out = (float*)d_out;

    char* w = (char*)d_ws;
    const size_t MB = 1u << 20;
    double* C64    = (double*)(w);                          // 2 MB
    double* S64    = (double*)(w + 2 * MB);                 // 2 MB
    double* CT64   = (double*)(w + 4 * MB);                 // 2 MB
    unsigned short* Pn = (unsigned short*)(w + 6 * MB);     // 1 MB (ks-major panel)
    int*    labels = (int*)   (w + 7 * MB);                 // 512 KB
    int*    list   = (int*)   (w + 7 * MB + 512 * 1024);    // 512 KB
    double* cn64   = (double*)(w + 8 * MB);                 // 16 KB
    float*  cn32   = (float*) (w + 8 * MB + 16 * 1024);     // 8 KB
    int*    counts = (int*)   (w + 8 * MB + 24 * 1024);     // 8 KB
    int*    counter= (int*)   (w + 8 * MB + 32 * 1024);     // 4 B

    init_kernel<<<(KC * D) / 256, 256, 0, stream>>>(initC, C64, CT64, Pn);

    for (int it = 0; it < ITERS; it++) {
        cnorm_kernel<<<KC / 4, 256, 0, stream>>>(C64, cn64, cn32, counter);
        assign_kernel<<<NP / 128, 512, 0, stream>>>(X, Pn, cn32, labels, list, counter);
        recheck_kernel<<<1024, 256, 0, stream>>>(X, CT64, cn64, list, counter, labels);
        accum_kernel<<<KC, 256, 0, stream>>>(X, labels, S64, counts);
        update_kernel<<<(KC * D) / 256, 256, 0, stream>>>(
            S64, counts, C64, CT64, Pn, (it == ITERS - 1) ? out : nullptr);
    }
    lab2f_kernel<<<NP / 256, 256, 0, stream>>>(labels, out + (size_t)KC * D);
}

// Round 13
// 2702.564 us; speedup vs baseline: 1.6259x; 1.1943x over previous
//
#include <hip/hip_runtime.h>
#include <hip/hip_bf16.h>

#define NP 131072
#define D 128
#define KC 2048
#define ITERS 5

#define TAU 0.03f      // bf16x3 top-2 gap below which we recheck in f64

#if defined(__has_builtin)
#if __has_builtin(__builtin_amdgcn_global_load_lds)
#define USE_GLL 1
#endif
#endif

typedef short bf16x8 __attribute__((ext_vector_type(8)));
typedef float f32x4 __attribute__((ext_vector_type(4)));

__device__ inline unsigned short f2bf(float x) {
    __hip_bfloat16 b = __float2bfloat16(x);
    return *reinterpret_cast<unsigned short*>(&b);
}
__device__ inline float bf2f(unsigned short u) {
    union { unsigned int i; float f; } c; c.i = ((unsigned int)u) << 16; return c.f;
}

// ks-major fragment panel: for cluster k, dim d:
//   g=k>>4, t15=k&15, ks=d>>5, q=(d>>3)&3, e=d&7, lane=q*16+t15
//   ushort idx = ((ks*128+g)*2 + hl)*512 + lane*8 + e
// => (ct,ks) chunk = groups ct*8..ct*8+8 = contiguous 16KB (gll-linear).
__device__ inline size_t pslot(int k, int d, int hl) {
    int g = k >> 4, t15 = k & 15, ks = d >> 5, q = (d >> 3) & 3, e = d & 7;
    return ((size_t)((ks * 128 + g) * 2 + hl)) * 512 + (q * 16 + t15) * 8 + e;
}

// ---------------------------------------------------------------------------
// init: C64 / CT64 / ks-major bf16 split panel
// ---------------------------------------------------------------------------
__global__ void init_kernel(const float* __restrict__ initC,
                            double* __restrict__ C64, double* __restrict__ CT64,
                            unsigned short* __restrict__ Pn) {
    int t = blockIdx.x * 256 + threadIdx.x;       // 262144
    float v = initC[t];
    C64[t] = (double)v;
    CT64[(size_t)(t & 127) * KC + (t >> 7)] = (double)v;
    unsigned short h = f2bf(v);
    int k = t >> 7, d = t & 127;
    Pn[pslot(k, d, 0)] = h;
    Pn[pslot(k, d, 1)] = f2bf(v - bf2f(h));
}

__global__ void cnorm_kernel(const double* __restrict__ C64,
                             double* __restrict__ n64, float* __restrict__ n32,
                             int* __restrict__ counter) {
    int r = blockIdx.x * 4 + (threadIdx.x >> 6);
    int lane = threadIdx.x & 63;
    double a = C64[(size_t)r * D + lane * 2];
    double b = C64[(size_t)r * D + lane * 2 + 1];
    double s = a * a + b * b;
#pragma unroll
    for (int m = 1; m < 64; m <<= 1) s += __shfl_xor(s, m, 64);
    if (lane == 0) { n64[r] = s; n32[r] = (float)s; }
    if (blockIdx.x == 0 && threadIdx.x == 0) *counter = 0;
}

// ---------------------------------------------------------------------------
// bf16x3 MFMA assign, m97-shaped. 256 threads = 4 waves (2 wrow x 2 wcol),
// BM=64 rows/block, grid 2048. A (64x128 h/l, 32KB) staged once -> a-frags
// hoisted to 64 VGPR -> A-LDS region REUSED as B double buffer (2x16KB).
// 64 steps (ct,ks): issue next B chunk via global_load_lds (panel is
// fragment-major-linear), 24 MFMA on cur buffer, ONE barrier per step.
// 34KB LDS -> 3-4 blocks/CU so barrier drains overlap across blocks (m114).
// ---------------------------------------------------------------------------
__global__ __launch_bounds__(256, 3)
void assign_kernel(const float* __restrict__ X,
                   const unsigned short* __restrict__ Pn,
                   const float* __restrict__ cnorm,
                   int* __restrict__ labels,
                   int* __restrict__ list,
                   int* __restrict__ counter) {
    __shared__ __align__(16) char lds[32768];     // A h/l then B dbuf 2x16KB
    __shared__ float mb1[128], mb2[128];
    __shared__ int mi1[128];

    const int tid = threadIdx.x;        // 0..255
    const int lane = tid & 63;
    const int wid = tid >> 6;           // 0..3
    const int wrow = wid >> 1;          // 0..1 (32-row half)
    const int wcol = wid & 1;           // 0..1 (64-col half per chunk)
    const int t15 = lane & 15;
    const int q = lane >> 4;            // 0..3
    const int pbase = blockIdx.x * 64;

    // ---- stage A tile (64 rows x 128 k), split to bf16 h/l ----
    // h region [0,16K), l region [16K,32K); row stride 256B
#pragma unroll
    for (int i = 0; i < 8; i++) {
        int f = i * 256 + tid;          // float4-slot over 64 rows x 32 slots
        int row = f >> 5, c4 = f & 31;
        float4 v = *(const float4*)&X[(size_t)(pbase + row) * D + c4 * 4];
        unsigned short h0 = f2bf(v.x), h1 = f2bf(v.y), h2 = f2bf(v.z), h3 = f2bf(v.w);
        unsigned short l0 = f2bf(v.x - bf2f(h0)), l1 = f2bf(v.y - bf2f(h1));
        unsigned short l2 = f2bf(v.z - bf2f(h2)), l3 = f2bf(v.w - bf2f(h3));
        uint2 ph = { (unsigned)h0 | ((unsigned)h1 << 16), (unsigned)h2 | ((unsigned)h3 << 16) };
        uint2 pl = { (unsigned)l0 | ((unsigned)l1 << 16), (unsigned)l2 | ((unsigned)l3 << 16) };
        int ad = row * 256 + c4 * 8;
        *(uint2*)(lds + ad) = ph;
        *(uint2*)(lds + 16384 + ad) = pl;
    }
    __syncthreads();

    // ---- hoist a-frags: rt=2 x ks=4 x {h,l} = 16 bf16x8 = 64 VGPR ----
    bf16x8 rah[2][4], ral[2][4];
#pragma unroll
    for (int rt = 0; rt < 2; rt++) {
        int row = wrow * 32 + rt * 16 + t15;
#pragma unroll
        for (int ks = 0; ks < 4; ks++) {
            int ad = row * 256 + ks * 64 + q * 16;
            rah[rt][ks] = *(const bf16x8*)(lds + ad);
            ral[rt][ks] = *(const bf16x8*)(lds + 16384 + ad);
        }
    }
    __syncthreads();   // A reads done; region becomes the B double buffer

    float b1[8], b2[8];
    int i1[8];
#pragma unroll
    for (int s = 0; s < 8; s++) { b1[s] = -INFINITY; b2[s] = -INFINITY; i1[s] = 0x7fffffff; }

    // B stage helper data: wave wid stages segments wid*4..wid*4+3 (1KB each)
    const char* PnB = (const char*)Pn;

    // prologue: stage (ct=0,ks=0) into buf0
#pragma unroll
    for (int i = 0; i < 4; i++) {
        int seg = wid * 4 + i;
        const char* src = PnB + seg * 1024;
#if USE_GLL
        __builtin_amdgcn_global_load_lds(
            (const __attribute__((address_space(1))) unsigned int*)(src + lane * 16),
            (__attribute__((address_space(3))) unsigned int*)(lds + seg * 1024),
            16, 0, 0);
#else
        uint4 v = *(const uint4*)(src + lane * 16);
        *(uint4*)(lds + seg * 1024 + lane * 16) = v;
#endif
    }
    __syncthreads();

    for (int ct = 0; ct < KC / 128; ct++) {
        f32x4 acc[2][4];
#pragma unroll
        for (int rt = 0; rt < 2; rt++)
#pragma unroll
            for (int cj = 0; cj < 4; cj++) acc[rt][cj] = (f32x4){0.f, 0.f, 0.f, 0.f};

#pragma unroll
        for (int ks = 0; ks < 4; ks++) {
            const int cur = (ct * 4 + ks) & 1;
            char* bcur = lds + cur * 16384;
            char* bnext = lds + (cur ^ 1) * 16384;

            // issue next chunk's staging (async under the MFMAs)
            const int nct = (ks == 3) ? ((ct < 15) ? ct + 1 : 15) : ct;
            const int nks = (ks + 1) & 3;
            const char* nsrc = PnB + ((size_t)(nks * 128 + nct * 8)) * 2048;
#pragma unroll
            for (int i = 0; i < 4; i++) {
                int seg = wid * 4 + i;
#if USE_GLL
                __builtin_amdgcn_global_load_lds(
                    (const __attribute__((address_space(1))) unsigned int*)(nsrc + seg * 1024 + lane * 16),
                    (__attribute__((address_space(3))) unsigned int*)(bnext + seg * 1024),
                    16, 0, 0);
#else
                uint4 v = *(const uint4*)(nsrc + seg * 1024 + lane * 16);
                *(uint4*)(bnext + seg * 1024 + lane * 16) = v;
#endif
            }

            // compute on bcur: b-frags contiguous (conflict-free), a from regs
#pragma unroll
            for (int cj = 0; cj < 4; cj++) {
                int gl = wcol * 4 + cj;
                bf16x8 bh = *(const bf16x8*)(bcur + gl * 2048 + lane * 16);
                bf16x8 bl = *(const bf16x8*)(bcur + gl * 2048 + 1024 + lane * 16);
#pragma unroll
                for (int rt = 0; rt < 2; rt++) {
                    acc[rt][cj] = __builtin_amdgcn_mfma_f32_16x16x32_bf16(rah[rt][ks], bh, acc[rt][cj], 0, 0, 0);
                    acc[rt][cj] = __builtin_amdgcn_mfma_f32_16x16x32_bf16(rah[rt][ks], bl, acc[rt][cj], 0, 0, 0);
                    acc[rt][cj] = __builtin_amdgcn_mfma_f32_16x16x32_bf16(ral[rt][ks], bh, acc[rt][cj], 0, 0, 0);
                }
            }
            __syncthreads();   // drains gll (next buf ready), frees cur
        }

        // epilogue: s = 2*dot - cn (xn dropped: row-shift invariant), top-2
#pragma unroll
        for (int cj = 0; cj < 4; cj++) {
            int col = ct * 128 + wcol * 64 + cj * 16 + t15;
            float cnv = cnorm[col];
#pragma unroll
            for (int rt = 0; rt < 2; rt++)
#pragma unroll
                for (int rg = 0; rg < 4; rg++) {
                    int s = rt * 4 + rg;
                    float sv = 2.0f * acc[rt][cj][rg] - cnv;
                    if (sv > b1[s]) { b2[s] = b1[s]; b1[s] = sv; i1[s] = col; }
                    else if (sv > b2[s]) b2[s] = sv;
                }
        }
    }

    // merge top-2 across the 16 t15 lanes of each q-group (within wave)
#pragma unroll
    for (int s = 0; s < 8; s++) {
#pragma unroll
        for (int m = 1; m < 16; m <<= 1) {
            float ob1 = __shfl_xor(b1[s], m, 64);
            int   oi  = __shfl_xor(i1[s], m, 64);
            float ob2 = __shfl_xor(b2[s], m, 64);
            if (ob1 > b1[s])      { b2[s] = fmaxf(b1[s], ob2); b1[s] = ob1; i1[s] = oi; }
            else if (ob1 < b1[s]) { b2[s] = fmaxf(b2[s], ob1); }
            else                  { b2[s] = b1[s]; i1[s] = (oi < i1[s]) ? oi : i1[s]; }
        }
    }

    // cross-wave merge (wcol 0 vs 1)
    if (t15 == 0) {
#pragma unroll
        for (int rt = 0; rt < 2; rt++)
#pragma unroll
            for (int rg = 0; rg < 4; rg++) {
                int s = rt * 4 + rg;
                int row = wrow * 32 + rt * 16 + q * 4 + rg;
                mb1[wcol * 64 + row] = b1[s];
                mb2[wcol * 64 + row] = b2[s];
                mi1[wcol * 64 + row] = i1[s];
            }
    }
    __syncthreads();
    if (tid < 64) {
        float a1 = mb1[tid], a2 = mb2[tid];  int ai = mi1[tid];
        float c1 = mb1[64 + tid], c2 = mb2[64 + tid];  int ci = mi1[64 + tid];
        float best, second;  int bi;
        if (a1 > c1)      { best = a1; bi = ai; second = fmaxf(a2, c1); }
        else if (a1 < c1) { best = c1; bi = ci; second = fmaxf(c2, a1); }
        else              { best = a1; bi = (ai < ci) ? ai : ci; second = a1; }
        int p = pbase + tid;
        labels[p] = bi;
        if (best - second < TAU) {
            int idx = atomicAdd(counter, 1);
            list[idx] = p;
        }
    }
}

// ---------------------------------------------------------------------------
// f64 recheck of flagged points: exact argmax over all 2048 clusters.
// ---------------------------------------------------------------------------
__global__ void recheck_kernel(const float* __restrict__ X,
                               const double* __restrict__ CT64,
                               const double* __restrict__ cn64,
                               const int* __restrict__ list,
                               const int* __restrict__ counter,
                               int* __restrict__ labels) {
    __shared__ float xrow[D];
    __shared__ double rb[4];
    __shared__ int ri[4];
    int cnt = *counter;
    for (int ii = blockIdx.x; ii < cnt; ii += gridDim.x) {
        int p = list[ii];
        __syncthreads();
        if (threadIdx.x < D) xrow[threadIdx.x] = X[(size_t)p * D + threadIdx.x];
        __syncthreads();
        double xn = 0.0;
#pragma unroll 16
        for (int d = 0; d < D; d++) {
            double xv = (double)xrow[d];
            xn = fma(xv, xv, xn);
        }
        double best = -1.0e300;
        int bi = 0x7fffffff;
#pragma unroll
        for (int g = 0; g < 8; g++) {
            int c = threadIdx.x + 256 * g;
            double acc = 0.0;
#pragma unroll 16
            for (int d = 0; d < D; d++)
                acc = fma((double)xrow[d], CT64[(size_t)d * KC + c], acc);
            double s = 2.0 * acc - xn - cn64[c];
            if (s > best || (s == best && c < bi)) { best = s; bi = c; }
        }
#pragma unroll
        for (int m = 1; m < 64; m <<= 1) {
            double ob = __shfl_xor(best, m, 64);
            int oi = __shfl_xor(bi, m, 64);
            if (ob > best || (ob == best && oi < bi)) { best = ob; bi = oi; }
        }
        int w = threadIdx.x >> 6;
        if ((threadIdx.x & 63) == 0) { rb[w] = best; ri[w] = bi; }
        __syncthreads();
        if (threadIdx.x == 0) {
            double bb = rb[0]; int bbi = ri[0];
            for (int w2 = 1; w2 < 4; w2++)
                if (rb[w2] > bb || (rb[w2] == bb && ri[w2] < bbi)) { bb = rb[w2]; bbi = ri[w2]; }
            labels[p] = bbi;
        }
    }
}

// ---------------------------------------------------------------------------
// Deterministic f64 segment sums: block per cluster; 4 waves scan fixed
// quarter-ranges with int4 label loads; LDS combine in fixed wave order.
// ---------------------------------------------------------------------------
__global__ void accum_kernel(const float* __restrict__ X,
                             const int* __restrict__ labels,
                             double* __restrict__ sums,
                             int* __restrict__ counts) {
    __shared__ double sred[4][D];
    __shared__ int cred[4];
    const int k = blockIdx.x;
    const int lane = threadIdx.x & 63;
    const int w = threadIdx.x >> 6;
    const int base0 = w * (NP / 4);
    double s0 = 0.0, s1 = 0.0;
    int cnt = 0;
    for (int it = 0; it < (NP / 4) / 256; it++) {
        int4 lab = *(const int4*)&labels[base0 + it * 256 + lane * 4];
#pragma unroll
        for (int j = 0; j < 4; j++) {
            int lv = (j == 0) ? lab.x : (j == 1) ? lab.y : (j == 2) ? lab.z : lab.w;
            unsigned long long m = __ballot(lv == k);
            cnt += __popcll(m);
            while (m) {
                int b = __ffsll(m) - 1;
                m &= m - 1;
                int p = base0 + it * 256 + b * 4 + j;
                float2 v = *(const float2*)&X[(size_t)p * D + lane * 2];
                s0 += (double)v.x;
                s1 += (double)v.y;
            }
        }
    }
    sred[w][lane * 2] = s0;
    sred[w][lane * 2 + 1] = s1;
    if (lane == 0) cred[w] = cnt;
    __syncthreads();
    if (threadIdx.x < D) {
        int d = threadIdx.x;
        double s = ((sred[0][d] + sred[1][d]) + sred[2][d]) + sred[3][d];
        sums[(size_t)k * D + d] = s;
    }
    if (threadIdx.x == 0)
        counts[k] = ((cred[0] + cred[1]) + cred[2]) + cred[3];
}

// ---------------------------------------------------------------------------
// update: C = count>0 ? sum/count : 0 (f64); mirror to CT64 + ks-major panel
// ---------------------------------------------------------------------------
__global__ void update_kernel(const double* __restrict__ sums,
                              const int* __restrict__ counts,
                              double* __restrict__ C64, double* __restrict__ CT64,
                              unsigned short* __restrict__ Pn,
                              float* __restrict__ outC) {
    int t = blockIdx.x * 256 + threadIdx.x;       // 262144
    int k = t >> 7;
    int n = counts[k];
    double v = (n > 0) ? sums[t] / (double)n : 0.0;
    C64[t] = v;
    CT64[(size_t)(t & 127) * KC + k] = v;
    float vf = (float)v;
    unsigned short h = f2bf(vf);
    int d = t & 127;
    Pn[pslot(k, d, 0)] = h;
    Pn[pslot(k, d, 1)] = f2bf(vf - bf2f(h));
    if (outC) outC[t] = vf;
}

__global__ void lab2f_kernel(const int* __restrict__ labels, float* __restrict__ out) {
    int t = blockIdx.x * 256 + threadIdx.x;
    out[t] = (float)labels[t];
}

extern "C" void kernel_launch(void* const* d_in, const int* in_sizes, int n_in,
                              void* d_out, int out_size, void* d_ws, size_t ws_size,
                              hipStream_t stream) {
    const float* X = (const float*)d_in[0];
    const float* initC = (const float*)d_in[1];
    float* out = (float*)d_out;

    char* w = (char*)d_ws;
    const size_t MB = 1u << 20;
    double* C64    = (double*)(w);                          // 2 MB
    double* S64    = (double*)(w + 2 * MB);                 // 2 MB
    double* CT64   = (double*)(w + 4 * MB);                 // 2 MB
    unsigned short* Pn = (unsigned short*)(w + 6 * MB);     // 1 MB (ks-major panel)
    int*    labels = (int*)   (w + 7 * MB);                 // 512 KB
    int*    list   = (int*)   (w + 7 * MB + 512 * 1024);    // 512 KB
    double* cn64   = (double*)(w + 8 * MB);                 // 16 KB
    float*  cn32   = (float*) (w + 8 * MB + 16 * 1024);     // 8 KB
    int*    counts = (int*)   (w + 8 * MB + 24 * 1024);     // 8 KB
    int*    counter= (int*)   (w + 8 * MB + 32 * 1024);     // 4 B

    init_kernel<<<(KC * D) / 256, 256, 0, stream>>>(initC, C64, CT64, Pn);

    for (int it = 0; it < ITERS; it++) {
        cnorm_kernel<<<KC / 4, 256, 0, stream>>>(C64, cn64, cn32, counter);
        assign_kernel<<<NP / 64, 256, 0, stream>>>(X, Pn, cn32, labels, list, counter);
        recheck_kernel<<<1024, 256, 0, stream>>>(X, CT64, cn64, list, counter, labels);
        accum_kernel<<<KC, 256, 0, stream>>>(X, labels, S64, counts);
        update_kernel<<<(KC * D) / 256, 256, 0, stream>>>(
            S64, counts, C64, CT64, Pn, (it == ITERS - 1) ? out : nullptr);
    }
    lab2f_kernel<<<NP / 256, 256, 0, stream>>>(labels, out + (size_t)KC * D);
}

// Round 14
// 2168.691 us; speedup vs baseline: 2.0262x; 1.2462x over previous
//
#include <hip/hip_runtime.h>
#include <hip/hip_bf16.h>

#define NP 131072
#define D 128
#define KC 2048
#define ITERS 5

#define TAU 0.03f      // bf16x3 top-2 gap below which we recheck in f64

#if defined(__has_builtin)
#if __has_builtin(__builtin_amdgcn_global_load_lds)
#define USE_GLL 1
#endif
#endif

typedef short bf16x8 __attribute__((ext_vector_type(8)));
typedef float f32x4 __attribute__((ext_vector_type(4)));

__device__ inline unsigned short f2bf(float x) {
    __hip_bfloat16 b = __float2bfloat16(x);
    return *reinterpret_cast<unsigned short*>(&b);
}
__device__ inline float bf2f(unsigned short u) {
    union { unsigned int i; float f; } c; c.i = ((unsigned int)u) << 16; return c.f;
}

// ks-major fragment panel: for cluster k, dim d:
//   g=k>>4, t15=k&15, ks=d>>5, q=(d>>3)&3, e=d&7, lane=q*16+t15
//   ushort idx = ((ks*128+g)*2 + hl)*512 + lane*8 + e
// => (ct,ks) chunk = groups ct*8..ct*8+8 = contiguous 16KB (gll-linear).
__device__ inline size_t pslot(int k, int d, int hl) {
    int g = k >> 4, t15 = k & 15, ks = d >> 5, q = (d >> 3) & 3, e = d & 7;
    return ((size_t)((ks * 128 + g) * 2 + hl)) * 512 + (q * 16 + t15) * 8 + e;
}

// ---------------------------------------------------------------------------
// init: C64 / CT64 / ks-major bf16 split panel
// ---------------------------------------------------------------------------
__global__ void init_kernel(const float* __restrict__ initC,
                            double* __restrict__ C64, double* __restrict__ CT64,
                            unsigned short* __restrict__ Pn) {
    int t = blockIdx.x * 256 + threadIdx.x;       // 262144
    float v = initC[t];
    C64[t] = (double)v;
    CT64[(size_t)(t & 127) * KC + (t >> 7)] = (double)v;
    unsigned short h = f2bf(v);
    int k = t >> 7, d = t & 127;
    Pn[pslot(k, d, 0)] = h;
    Pn[pslot(k, d, 1)] = f2bf(v - bf2f(h));
}

__global__ void cnorm_kernel(const double* __restrict__ C64,
                             double* __restrict__ n64, float* __restrict__ n32,
                             int* __restrict__ counter) {
    int r = blockIdx.x * 4 + (threadIdx.x >> 6);
    int lane = threadIdx.x & 63;
    double a = C64[(size_t)r * D + lane * 2];
    double b = C64[(size_t)r * D + lane * 2 + 1];
    double s = a * a + b * b;
#pragma unroll
    for (int m = 1; m < 64; m <<= 1) s += __shfl_xor(s, m, 64);
    if (lane == 0) { n64[r] = s; n32[r] = (float)s; }
    if (blockIdx.x == 0 && threadIdx.x == 0) *counter = 0;
}

// ---------------------------------------------------------------------------
// bf16x3 MFMA assign, m97-shaped. 256 threads = 4 waves (2 wrow x 2 wcol),
// BM=64 rows/block, grid 2048. A (64x128 h/l, swizzled) staged once ->
// a-frags hoisted to 64 VGPR -> A-LDS REUSED as B double buffer (2x16KB).
// 64 steps: gll-stage next chunk, setprio-wrapped 24 MFMA, one barrier.
// R14: branchless top-2, A-swizzle back (R13: 3.67M prologue conflicts),
// setprio, LDS exactly 32KB (merge aliased) + launch_bounds(256,4).
// ---------------------------------------------------------------------------
__global__ __launch_bounds__(256, 4)
void assign_kernel(const float* __restrict__ X,
                   const unsigned short* __restrict__ Pn,
                   const float* __restrict__ cnorm,
                   int* __restrict__ labels,
                   int* __restrict__ list,
                   int* __restrict__ counter) {
    __shared__ __align__(16) char lds[32768];     // A h/l -> B dbuf 2x16KB -> merge

    const int tid = threadIdx.x;        // 0..255
    const int lane = tid & 63;
    const int wid = tid >> 6;           // 0..3
    const int wrow = wid >> 1;          // 0..1 (32-row half)
    const int wcol = wid & 1;           // 0..1 (64-col half per chunk)
    const int t15 = lane & 15;
    const int q = lane >> 4;            // 0..3
    const int pbase = blockIdx.x * 64;

    // ---- stage A tile (64 rows x 128 k), split to bf16 h/l, XOR-swizzled ----
#pragma unroll
    for (int i = 0; i < 8; i++) {
        int f = i * 256 + tid;          // float4-slot over 64 rows x 32 slots
        int row = f >> 5, c4 = f & 31;
        float4 v = *(const float4*)&X[(size_t)(pbase + row) * D + c4 * 4];
        unsigned short h0 = f2bf(v.x), h1 = f2bf(v.y), h2 = f2bf(v.z), h3 = f2bf(v.w);
        unsigned short l0 = f2bf(v.x - bf2f(h0)), l1 = f2bf(v.y - bf2f(h1));
        unsigned short l2 = f2bf(v.z - bf2f(h2)), l3 = f2bf(v.w - bf2f(h3));
        uint2 ph = { (unsigned)h0 | ((unsigned)h1 << 16), (unsigned)h2 | ((unsigned)h3 << 16) };
        uint2 pl = { (unsigned)l0 | ((unsigned)l1 << 16), (unsigned)l2 | ((unsigned)l3 << 16) };
        int ad = (row * 256 + c4 * 8) ^ ((row & 7) << 4);
        *(uint2*)(lds + ad) = ph;
        *(uint2*)(lds + 16384 + ad) = pl;
    }
    __syncthreads();

    // ---- hoist a-frags: rt=2 x ks=4 x {h,l} = 16 bf16x8 = 64 VGPR ----
    bf16x8 rah[2][4], ral[2][4];
#pragma unroll
    for (int rt = 0; rt < 2; rt++) {
        int row = wrow * 32 + rt * 16 + t15;
        int sw = (row & 7) << 4;
#pragma unroll
        for (int ks = 0; ks < 4; ks++) {
            int ad = (row * 256 + ks * 64 + q * 16) ^ sw;
            rah[rt][ks] = *(const bf16x8*)(lds + ad);
            ral[rt][ks] = *(const bf16x8*)(lds + 16384 + ad);
        }
    }
    __syncthreads();   // A reads done; region becomes the B double buffer

    float b1[8], b2[8];
    int i1[8];
#pragma unroll
    for (int s = 0; s < 8; s++) { b1[s] = -INFINITY; b2[s] = -INFINITY; i1[s] = 0x7fffffff; }

    // B stage helper: wave wid stages segments wid*4..wid*4+3 (1KB each)
    const char* PnB = (const char*)Pn;

    // prologue: stage (ct=0,ks=0) into buf0
#pragma unroll
    for (int i = 0; i < 4; i++) {
        int seg = wid * 4 + i;
        const char* src = PnB + seg * 1024;
#if USE_GLL
        __builtin_amdgcn_global_load_lds(
            (const __attribute__((address_space(1))) unsigned int*)(src + lane * 16),
            (__attribute__((address_space(3))) unsigned int*)(lds + seg * 1024),
            16, 0, 0);
#else
        uint4 v = *(const uint4*)(src + lane * 16);
        *(uint4*)(lds + seg * 1024 + lane * 16) = v;
#endif
    }
    __syncthreads();

    for (int ct = 0; ct < KC / 128; ct++) {
        f32x4 acc[2][4];
#pragma unroll
        for (int rt = 0; rt < 2; rt++)
#pragma unroll
            for (int cj = 0; cj < 4; cj++) acc[rt][cj] = (f32x4){0.f, 0.f, 0.f, 0.f};

#pragma unroll
        for (int ks = 0; ks < 4; ks++) {
            const int cur = (ct * 4 + ks) & 1;
            char* bcur = lds + cur * 16384;
            char* bnext = lds + (cur ^ 1) * 16384;

            // issue next chunk's staging (async under the MFMAs)
            const int nct = (ks == 3) ? ((ct < 15) ? ct + 1 : 15) : ct;
            const int nks = (ks + 1) & 3;
            const char* nsrc = PnB + ((size_t)(nks * 128 + nct * 8)) * 2048;
#pragma unroll
            for (int i = 0; i < 4; i++) {
                int seg = wid * 4 + i;
#if USE_GLL
                __builtin_amdgcn_global_load_lds(
                    (const __attribute__((address_space(1))) unsigned int*)(nsrc + seg * 1024 + lane * 16),
                    (__attribute__((address_space(3))) unsigned int*)(bnext + seg * 1024),
                    16, 0, 0);
#else
                uint4 v = *(const uint4*)(nsrc + seg * 1024 + lane * 16);
                *(uint4*)(bnext + seg * 1024 + lane * 16) = v;
#endif
            }

            // compute on bcur: b-frags contiguous (conflict-free), a from regs
            __builtin_amdgcn_s_setprio(1);
#pragma unroll
            for (int cj = 0; cj < 4; cj++) {
                int gl = wcol * 4 + cj;
                bf16x8 bh = *(const bf16x8*)(bcur + gl * 2048 + lane * 16);
                bf16x8 bl = *(const bf16x8*)(bcur + gl * 2048 + 1024 + lane * 16);
#pragma unroll
                for (int rt = 0; rt < 2; rt++) {
                    acc[rt][cj] = __builtin_amdgcn_mfma_f32_16x16x32_bf16(rah[rt][ks], bh, acc[rt][cj], 0, 0, 0);
                    acc[rt][cj] = __builtin_amdgcn_mfma_f32_16x16x32_bf16(rah[rt][ks], bl, acc[rt][cj], 0, 0, 0);
                    acc[rt][cj] = __builtin_amdgcn_mfma_f32_16x16x32_bf16(ral[rt][ks], bh, acc[rt][cj], 0, 0, 0);
                }
            }
            __builtin_amdgcn_s_setprio(0);
            __syncthreads();   // drains gll (next buf ready), frees cur
        }

        // epilogue: s = 2*dot - cn (xn dropped), BRANCHLESS top-2
#pragma unroll
        for (int cj = 0; cj < 4; cj++) {
            int col = ct * 128 + wcol * 64 + cj * 16 + t15;
            float cnv = cnorm[col];
#pragma unroll
            for (int rt = 0; rt < 2; rt++)
#pragma unroll
                for (int rg = 0; rg < 4; rg++) {
                    int s = rt * 4 + rg;
                    float sv = __builtin_fmaf(2.0f, acc[rt][cj][rg], -cnv);
                    bool gt1 = sv > b1[s];
                    float mx2 = fmaxf(b2[s], sv);
                    b2[s] = gt1 ? b1[s] : mx2;
                    i1[s] = gt1 ? col : i1[s];
                    b1[s] = gt1 ? sv : b1[s];
                }
        }
    }

    // merge top-2 across the 16 t15 lanes of each q-group (branchless)
#pragma unroll
    for (int s = 0; s < 8; s++) {
#pragma unroll
        for (int m = 1; m < 16; m <<= 1) {
            float ob1 = __shfl_xor(b1[s], m, 64);
            int   oi  = __shfl_xor(i1[s], m, 64);
            float ob2 = __shfl_xor(b2[s], m, 64);
            bool gt = ob1 > b1[s];
            bool eq = ob1 == b1[s];
            float nb2 = gt ? fmaxf(b1[s], ob2) : fmaxf(b2[s], ob1);
            nb2 = eq ? b1[s] : nb2;
            int ni = gt ? oi : i1[s];
            ni = (eq && oi < i1[s]) ? oi : ni;
            b1[s] = gt ? ob1 : b1[s];
            b2[s] = nb2;
            i1[s] = ni;
        }
    }

    // cross-wave merge (wcol 0 vs 1) via LDS aliased onto dead B region
    __syncthreads();                          // all B reads done (last step)
    float* mb1 = (float*)lds;                 // [2][64]
    float* mb2 = ((float*)lds) + 128;         // [2][64]
    int*   mi1 = (int*)(((float*)lds) + 256); // [2][64]
    if (t15 == 0) {
#pragma unroll
        for (int rt = 0; rt < 2; rt++)
#pragma unroll
            for (int rg = 0; rg < 4; rg++) {
                int s = rt * 4 + rg;
                int row = wrow * 32 + rt * 16 + q * 4 + rg;
                mb1[wcol * 64 + row] = b1[s];
                mb2[wcol * 64 + row] = b2[s];
                mi1[wcol * 64 + row] = i1[s];
            }
    }
    __syncthreads();
    if (tid < 64) {
        float a1 = mb1[tid], a2 = mb2[tid];  int ai = mi1[tid];
        float c1 = mb1[64 + tid], c2 = mb2[64 + tid];  int ci = mi1[64 + tid];
        float best, second;  int bi;
        if (a1 > c1)      { best = a1; bi = ai; second = fmaxf(a2, c1); }
        else if (a1 < c1) { best = c1; bi = ci; second = fmaxf(c2, a1); }
        else              { best = a1; bi = (ai < ci) ? ai : ci; second = a1; }
        int p = pbase + tid;
        labels[p] = bi;
        if (best - second < TAU) {
            int idx = atomicAdd(counter, 1);
            list[idx] = p;
        }
    }
}

// ---------------------------------------------------------------------------
// f64 recheck of flagged points: exact argmax over all 2048 clusters.
// ---------------------------------------------------------------------------
__global__ void recheck_kernel(const float* __restrict__ X,
                               const double* __restrict__ CT64,
                               const double* __restrict__ cn64,
                               const int* __restrict__ list,
                               const int* __restrict__ counter,
                               int* __restrict__ labels) {
    __shared__ float xrow[D];
    __shared__ double rb[4];
    __shared__ int ri[4];
    int cnt = *counter;
    for (int ii = blockIdx.x; ii < cnt; ii += gridDim.x) {
        int p = list[ii];
        __syncthreads();
        if (threadIdx.x < D) xrow[threadIdx.x] = X[(size_t)p * D + threadIdx.x];
        __syncthreads();
        double xn = 0.0;
#pragma unroll 16
        for (int d = 0; d < D; d++) {
            double xv = (double)xrow[d];
            xn = fma(xv, xv, xn);
        }
        double best = -1.0e300;
        int bi = 0x7fffffff;
#pragma unroll
        for (int g = 0; g < 8; g++) {
            int c = threadIdx.x + 256 * g;
            double acc = 0.0;
#pragma unroll 16
            for (int d = 0; d < D; d++)
                acc = fma((double)xrow[d], CT64[(size_t)d * KC + c], acc);
            double s = 2.0 * acc - xn - cn64[c];
            if (s > best || (s == best && c < bi)) { best = s; bi = c; }
        }
#pragma unroll
        for (int m = 1; m < 64; m <<= 1) {
            double ob = __shfl_xor(best, m, 64);
            int oi = __shfl_xor(bi, m, 64);
            if (ob > best || (ob == best && oi < bi)) { best = ob; bi = oi; }
        }
        int w = threadIdx.x >> 6;
        if ((threadIdx.x & 63) == 0) { rb[w] = best; ri[w] = bi; }
        __syncthreads();
        if (threadIdx.x == 0) {
            double bb = rb[0]; int bbi = ri[0];
            for (int w2 = 1; w2 < 4; w2++)
                if (rb[w2] > bb || (rb[w2] == bb && ri[w2] < bbi)) { bb = rb[w2]; bbi = ri[w2]; }
            labels[p] = bbi;
        }
    }
}

// ---------------------------------------------------------------------------
// Deterministic f64 segment sums: block per cluster; 4 waves scan fixed
// quarter-ranges with int4 label loads; LDS combine in fixed wave order.
// ---------------------------------------------------------------------------
__global__ void accum_kernel(const float* __restrict__ X,
                             const int* __restrict__ labels,
                             double* __restrict__ sums,
                             int* __restrict__ counts) {
    __shared__ double sred[4][D];
    __shared__ int cred[4];
    const int k = blockIdx.x;
    const int lane = threadIdx.x & 63;
    const int w = threadIdx.x >> 6;
    const int base0 = w * (NP / 4);
    double s0 = 0.0, s1 = 0.0;
    int cnt = 0;
    for (int it = 0; it < (NP / 4) / 256; it++) {
        int4 lab = *(const int4*)&labels[base0 + it * 256 + lane * 4];
#pragma unroll
        for (int j = 0; j < 4; j++) {
            int lv = (j == 0) ? lab.x : (j == 1) ? lab.y : (j == 2) ? lab.z : lab.w;
            unsigned long long m = __ballot(lv == k);
            cnt += __popcll(m);
            while (m) {
                int b = __ffsll(m) - 1;
                m &= m - 1;
                int p = base0 + it * 256 + b * 4 + j;
                float2 v = *(const float2*)&X[(size_t)p * D + lane * 2];
                s0 += (double)v.x;
                s1 += (double)v.y;
            }
        }
    }
    sred[w][lane * 2] = s0;
    sred[w][lane * 2 + 1] = s1;
    if (lane == 0) cred[w] = cnt;
    __syncthreads();
    if (threadIdx.x < D) {
        int d = threadIdx.x;
        double s = ((sred[0][d] + sred[1][d]) + sred[2][d]) + sred[3][d];
        sums[(size_t)k * D + d] = s;
    }
    if (threadIdx.x == 0)
        counts[k] = ((cred[0] + cred[1]) + cred[2]) + cred[3];
}

// ---------------------------------------------------------------------------
// update: C = count>0 ? sum/count : 0 (f64); mirror to CT64 + ks-major panel
// ---------------------------------------------------------------------------
__global__ void update_kernel(const double* __restrict__ sums,
                              const int* __restrict__ counts,
                              double* __restrict__ C64, double* __restrict__ CT64,
                              unsigned short* __restrict__ Pn,
                              float* __restrict__ outC) {
    int t = blockIdx.x * 256 + threadIdx.x;       // 262144
    int k = t >> 7;
    int n = counts[k];
    double v = (n > 0) ? sums[t] / (double)n : 0.0;
    C64[t] = v;
    CT64[(size_t)(t & 127) * KC + k] = v;
    float vf = (float)v;
    unsigned short h = f2bf(vf);
    int d = t & 127;
    Pn[pslot(k, d, 0)] = h;
    Pn[pslot(k, d, 1)] = f2bf(vf - bf2f(h));
    if (outC) outC[t] = vf;
}

__global__ void lab2f_kernel(const int* __restrict__ labels, float* __restrict__ out) {
    int t = blockIdx.x * 256 + threadIdx.x;
    out[t] = (float)labels[t];
}

extern "C" void kernel_launch(void* const* d_in, const int* in_sizes, int n_in,
                              void* d_out, int out_size, void* d_ws, size_t ws_size,
                              hipStream_t stream) {
    const float* X = (const float*)d_in[0];
    const float* initC = (const float*)d_in[1];
    float* out = (float*)d_out;

    char* w = (char*)d_ws;
    const size_t MB = 1u << 20;
    double* C64    = (double*)(w);                          // 2 MB
    double* S64    = (double*)(w + 2 * MB);                 // 2 MB
    double* CT64   = (double*)(w + 4 * MB);                 // 2 MB
    unsigned short* Pn = (unsigned short*)(w + 6 * MB);     // 1 MB (ks-major panel)
    int*    labels = (int*)   (w + 7 * MB);                 // 512 KB
    int*    list   = (int*)   (w + 7 * MB + 512 * 1024);    // 512 KB
    double* cn64   = (double*)(w + 8 * MB);                 // 16 KB
    float*  cn32   = (float*) (w + 8 * MB + 16 * 1024);     // 8 KB
    int*    counts = (int*)   (w + 8 * MB + 24 * 1024);     // 8 KB
    int*    counter= (int*)   (w + 8 * MB + 32 * 1024);     // 4 B

    init_kernel<<<(KC * D) / 256, 256, 0, stream>>>(initC, C64, CT64, Pn);

    for (int it = 0; it < ITERS; it++) {
        cnorm_kernel<<<KC / 4, 256, 0, stream>>>(C64, cn64, cn32, counter);
        assign_kernel<<<NP / 64, 256, 0, stream>>>(X, Pn, cn32, labels, list, counter);
        recheck_kernel<<<1024, 256, 0, stream>>>(X, CT64, cn64, list, counter, labels);
        accum_kernel<<<KC, 256, 0, stream>>>(X, labels, S64, counts);
        update_kernel<<<(KC * D) / 256, 256, 0, stream>>>(
            S64, counts, C64, CT64, Pn, (it == ITERS - 1) ? out : nullptr);
    }
    lab2f_kernel<<<NP / 256, 256, 0, stream>>>(labels, out + (size_t)KC * D);
}